// Round 15
// baseline (375.837 us; speedup 1.0000x reference)
//
#include <hip/hip_runtime.h>

// GAT encoder, MI355X. Algebraic fold: edge features only enter via the logit
// a_edge = edge_attr(4) @ M[l](4x4) + c0[l](4). CSR-by-dst built ATOMIC-FREE
// (device atomics are serviced memory-side; R8-R10). Bucketing: per-block LDS
// histogram (bin=dst>>8) -> bin-major scan (block offsets folded into consumers;
// no scanC pass) -> LDS-rank scatter -> per-bucket exact CSR with LDS counters
// + BUCKET-LOCAL DEGREE SORT emitting perm[] (64-bin LDS counting sort; R14:
// ~27% of edge iterations wasted on degree imbalance in node-packed waves).
// Edge record = uint2 {src, edge_attr as 4xfp8-e4m3}. Node state h BF16; xs
// bf16. k_gat: EIGHT nodes per wave via perm (8-lane groups, 1 edge/iter;
// sorted co-scheduling -> no imbalance; NO cross-lane reductions at all),
// depth-2 pipeline, exp2-domain logits. Fused softmax + bias + residual + LN
// + ReLU.

#define LRELU_SLOPE 0.2f
#define LOG2E 1.4426950408889634f
#define P1B 512            // pass-1 blocks (private ranges per (bin,block))
#define NBKT_MAX 512       // max buckets (N <= 131072)

typedef float f32x2 __attribute__((ext_vector_type(2)));

#ifdef __has_builtin
#if __has_builtin(__builtin_amdgcn_fdot2_f32_bf16)
#define HAS_BF16DOT 1
#endif
#endif
#ifndef HAS_BF16DOT
#define HAS_BF16DOT 0
#endif

#if HAS_BF16DOT
typedef __bf16 bf16x2_t __attribute__((ext_vector_type(2)));
#endif

__device__ __forceinline__ f32x2 fp8lo(unsigned int v) {
    return __builtin_amdgcn_cvt_pk_f32_fp8((int)v, false);
}
__device__ __forceinline__ f32x2 fp8hi(unsigned int v) {
    return __builtin_amdgcn_cvt_pk_f32_fp8((int)v, true);
}
__device__ __forceinline__ ushort f2bf(float x) {
    unsigned int b = __float_as_uint(x);
    return (ushort)((b + 0x7fffu + ((b >> 16) & 1u)) >> 16);   // RNE
}
__device__ __forceinline__ unsigned int pack2bf(float a, float b) {
    return (unsigned int)f2bf(a) | ((unsigned int)f2bf(b) << 16);
}
__device__ __forceinline__ float bf_lo(unsigned int v) { return __uint_as_float(v << 16); }
__device__ __forceinline__ float bf_hi(unsigned int v) { return __uint_as_float(v & 0xffff0000u); }

__device__ __forceinline__ float dot2bf(unsigned int a, unsigned int b, float c) {
#if HAS_BF16DOT
    return __builtin_amdgcn_fdot2_f32_bf16(__builtin_bit_cast(bf16x2_t, a),
                                           __builtin_bit_cast(bf16x2_t, b), c, false);
#else
    return fmaf(bf_lo(a), bf_lo(b), fmaf(bf_hi(a), bf_hi(b), c));
#endif
}

// ---- fused: block 0 = weight folding; blocks 1.. = h0 = x @ node_w + node_b ----
__global__ void k_prep0(const float* __restrict__ lin_edge_w, // [3][64][64]
                        const float* __restrict__ att_edge,   // [3][4][16]
                        const float* __restrict__ edge_w,     // [4][64]
                        const float* __restrict__ edge_b,     // [64]
                        float* __restrict__ Mc,               // [48] M + [12] c0
                        const float* __restrict__ x, const float* __restrict__ nw,
                        const float* __restrict__ nb, ushort* __restrict__ hbf,
                        int n_nodes)
{
    __shared__ float we[3][64][4];
    int t = threadIdx.x;
    if (blockIdx.x == 0) {
        if (t < 192) {
            int l = t >> 6, k = t & 63;
            for (int h = 0; h < 4; ++h) {
                float acc = 0.f;
                #pragma unroll
                for (int c = 0; c < 16; ++c)
                    acc = fmaf(lin_edge_w[l*4096 + k*64 + h*16 + c],
                               att_edge[l*64 + h*16 + c], acc);
                we[l][k][h] = acc;
            }
        }
        __syncthreads();
        if (t < 48) {
            int l = t >> 4, k4 = (t >> 2) & 3, h = t & 3;
            float acc = 0.f;
            for (int k = 0; k < 64; ++k)
                acc = fmaf(edge_w[k4*64 + k], we[l][k][h], acc);
            Mc[l*16 + k4*4 + h] = acc * LOG2E;
        }
        if (t >= 64 && t < 76) {
            int u = t - 64, l = u >> 2, h = u & 3;
            float acc = 0.f;
            for (int k = 0; k < 64; ++k)
                acc = fmaf(edge_b[k], we[l][k][h], acc);
            Mc[48 + l*4 + h] = acc * LOG2E;
        }
        return;
    }
    int idx = (blockIdx.x - 1) * blockDim.x + t;
    int n = idx >> 6, j = idx & 63;
    if (n >= n_nodes) return;
    float acc = nb[j];
    #pragma unroll
    for (int k = 0; k < 8; ++k) acc = fmaf(x[n*8 + k], nw[k*64 + j], acc);
    hbf[(size_t)n*64 + j] = f2bf(acc);
}

// ---- pass 1a: per-block LDS histogram over buckets (bin = dst>>8) ----
__global__ __launch_bounds__(256) void k_hist1(const int* __restrict__ dst,
                                               int* __restrict__ C,
                                               int E, int chunk, int nbkt) {
    __shared__ int h[NBKT_MAX];
    int b = blockIdx.x, t = threadIdx.x;
    for (int i = t; i < nbkt; i += 256) h[i] = 0;
    __syncthreads();
    int e0 = b*chunk, e1 = min(e0 + chunk, E);
    for (int e = e0 + t; e < e1; e += 256)
        atomicAdd(&h[dst[e] >> 8], 1);
    __syncthreads();
    for (int i = t; i < nbkt; i += 256) C[i*P1B + b] = h[i];
}

// ---- scan: per-1024-chunk inclusive (scanA) + block-offset scan (scanB);
//      consumers add bsum[(idx)>>10] themselves (no scanC pass) ----
__global__ void k_scanA(const int* __restrict__ in, int* __restrict__ out,
                        int* __restrict__ bsum, int n) {
    __shared__ int s[1024];
    int i = blockIdx.x*1024 + threadIdx.x;
    s[threadIdx.x] = (i < n) ? in[i] : 0;
    __syncthreads();
    for (int off = 1; off < 1024; off <<= 1) {
        int t = (threadIdx.x >= off) ? s[threadIdx.x - off] : 0;
        __syncthreads();
        s[threadIdx.x] += t;
        __syncthreads();
    }
    if (i < n) out[i] = s[threadIdx.x];               // inclusive chunk scan
    if (threadIdx.x == 1023) bsum[blockIdx.x] = s[1023];
}

__global__ void k_scanB(int* bsum, int nb) {          // nb <= 1024, 1 block
    __shared__ int s[1024];
    int t = threadIdx.x;
    int own = (t < nb) ? bsum[t] : 0;
    s[t] = own;
    __syncthreads();
    for (int off = 1; off < 1024; off <<= 1) {
        int v = (t >= off) ? s[t - off] : 0;
        __syncthreads();
        s[t] += v;
        __syncthreads();
    }
    if (t < nb) bsum[t] = s[t] - own;                 // exclusive block offsets
}

__device__ __forceinline__ int scanned(const int* S, const int* bsum, int idx) {
    return S[idx] + bsum[idx >> 10];                  // full inclusive value
}

// ---- pass 1b: scatter edges into bucket-contiguous staging, LDS ranks only ----
__global__ __launch_bounds__(256) void k_scat1(const int* __restrict__ dst,
        const int* __restrict__ srcv, const float4* __restrict__ ea,
        const int* __restrict__ S, const int* __restrict__ bsum,
        uint2* __restrict__ brec, int E, int chunk, int nbkt) {
    __shared__ int base[NBKT_MAX];
    __shared__ int cur[NBKT_MAX];
    int b = blockIdx.x, t = threadIdx.x;
    for (int i = t; i < nbkt; i += 256) {
        int flat = i*P1B + b;
        base[i] = flat ? scanned(S, bsum, flat - 1) : 0;
        cur[i] = 0;
    }
    __syncthreads();
    int e0 = b*chunk, e1 = min(e0 + chunk, E);
    for (int e = e0 + t; e < e1; e += 256) {
        int d = dst[e];
        int bin = d >> 8;
        int lr = atomicAdd(&cur[bin], 1);             // LDS atomic
        int slot = base[bin] + lr;
        float4 v = ea[e];
        unsigned int p = (unsigned int)__builtin_amdgcn_cvt_pk_fp8_f32(v.x, v.y, 0, false);
        p = (unsigned int)__builtin_amdgcn_cvt_pk_fp8_f32(v.z, v.w, (int)p, true);
        uint2 r;
        r.x = (unsigned int)srcv[e] | ((unsigned int)(d & 255) << 24); // src<2^17
        r.y = p;
        brec[slot] = r;
    }
}

// ---- pass 2: per-bucket exact CSR + bucket-local degree-sort perm ----
__global__ __launch_bounds__(256) void k_csr(const uint2* __restrict__ brec,
        const int* __restrict__ S, const int* __restrict__ bsum,
        uint2* __restrict__ recs, int* __restrict__ rowptr, int* __restrict__ perm,
        int nbkt, int NN, int E) {
    int bkt = blockIdx.x, t = threadIdx.x;
    __shared__ int cnt[256], exc[256], cur[256], ssc[256];
    __shared__ int dh[64], dsc[64], dcu[64];
    int ib = bkt*P1B - 1, ie = (bkt + 1)*P1B - 1;
    int seg_b = bkt ? scanned(S, bsum, ib) : 0;
    int seg_e = scanned(S, bsum, ie);
    cnt[t] = 0; cur[t] = 0;
    if (t < 64) { dh[t] = 0; dcu[t] = 0; }
    __syncthreads();
    for (int i = seg_b + t; i < seg_e; i += 256)
        atomicAdd(&cnt[brec[i].x >> 24], 1);          // LDS atomic
    __syncthreads();
    ssc[t] = cnt[t];
    __syncthreads();
    for (int off = 1; off < 256; off <<= 1) {
        int v = (t >= off) ? ssc[t - off] : 0;
        __syncthreads();
        ssc[t] += v;
        __syncthreads();
    }
    exc[t] = ssc[t] - cnt[t];
    __syncthreads();
    int g = bkt*256 + t;
    bool valid = (g < NN);
    if (valid) rowptr[g] = seg_b + exc[t];            // global CSR offset
    if (bkt == nbkt - 1 && t == 0) rowptr[NN] = E;
    // degree histogram (64 bins, clamp) for bucket-local counting sort
    int dcl = valid ? min(cnt[t], 63) : 0;
    if (valid) atomicAdd(&dh[dcl], 1);
    __syncthreads();
    if (t < 64) dsc[t] = dh[t];
    __syncthreads();
    for (int off = 1; off < 64; off <<= 1) {
        int v = (t >= off && t < 64) ? dsc[t - off] : 0;
        __syncthreads();
        if (t < 64) dsc[t] += v;
        __syncthreads();
    }
    if (valid) {
        int slot = (dsc[dcl] - dh[dcl]) + atomicAdd(&dcu[dcl], 1);
        perm[bkt*256 + slot] = g;                     // degree-sorted within bucket
    }
    // placement pass
    for (int i = seg_b + t; i < seg_e; i += 256) {
        uint2 r = brec[i];
        int dl = (int)(r.x >> 24);
        int slot = seg_b + exc[dl] + atomicAdd(&cur[dl], 1);
        r.x &= 0x00FFFFFFu;
        recs[slot] = r;
    }
}

__global__ void k_eamean(const int* __restrict__ rowptr, const uint2* __restrict__ recs,
                         float4* __restrict__ ea_mean, int n) {
    int i = blockIdx.x*blockDim.x + threadIdx.x;
    if (i >= n) return;
    int b = rowptr[i], e = rowptr[i + 1];
    float sx = 0.f, sy = 0.f, sz = 0.f, sw = 0.f;
    for (int s = b; s < e; ++s) {
        unsigned int p = recs[s].y;
        f32x2 lo = fp8lo(p), hi = fp8hi(p);
        sx += lo.x; sy += lo.y; sz += hi.x; sw += hi.y;
    }
    float inv = (e > b) ? 1.f / (float)(e - b) : 0.f;  // deg=0 -> e_mean = 0
    ea_mean[i] = make_float4(sx*inv, sy*inv, sz*inv, sw*inv);
}

// ---- per layer: xs = h @ lin_w[l] (bf16 in/out, bf16-pair dot); 4 nodes/wave ----
__global__ __launch_bounds__(256) void k_proj(const ushort* __restrict__ hbf,
        const float* __restrict__ lw,   // lin_w + l*4096
        const float* __restrict__ asw,  // att_src + l*64
        const float* __restrict__ adw,  // att_dst + l*64
        ushort* __restrict__ xs2, float* __restrict__ a_src4,
        float* __restrict__ a_dst4, int n_nodes)
{
    __shared__ unsigned int Wp[2048];   // [k2=32][c=64] bf16 pairs (k even/odd)
    for (int i = threadIdx.x; i < 2048; i += 256) {
        int k2 = i >> 6, c = i & 63;
        Wp[i] = pack2bf(lw[(k2*2)*64 + c], lw[(k2*2+1)*64 + c]);
    }
    __syncthreads();
    int lane = threadIdx.x & 63, wid = threadIdx.x >> 6;
    float as_w = asw[lane] * LOG2E, ad_w = adw[lane] * LOG2E;  // exp2-domain logits
    int nquads = (n_nodes + 3) >> 2;
    int nlast = n_nodes - 1;
    for (int q = blockIdx.x*4 + wid; q < nquads; q += gridDim.x*4) {
        int n0 = q << 2;
        int n1 = min(n0+1, nlast), n2 = min(n0+2, nlast), n3 = min(n0+3, nlast);
        const uint4* r0p = (const uint4*)(hbf + (size_t)n0*64);
        const uint4* r1p = (const uint4*)(hbf + (size_t)n1*64);
        const uint4* r2p = (const uint4*)(hbf + (size_t)n2*64);
        const uint4* r3p = (const uint4*)(hbf + (size_t)n3*64);
        float acc0 = 0.f, acc1 = 0.f, acc2 = 0.f, acc3 = 0.f;
        #pragma unroll
        for (int qq = 0; qq < 8; ++qq) {               // 8 x (4 pairs = 8 k)
            uint4 u0 = r0p[qq], u1 = r1p[qq], u2 = r2p[qq], u3 = r3p[qq];
            unsigned int w0 = Wp[(qq*4+0)*64 + lane];
            unsigned int w1 = Wp[(qq*4+1)*64 + lane];
            unsigned int w2 = Wp[(qq*4+2)*64 + lane];
            unsigned int w3 = Wp[(qq*4+3)*64 + lane];
            acc0 = dot2bf(u0.w, w3, dot2bf(u0.z, w2, dot2bf(u0.y, w1, dot2bf(u0.x, w0, acc0))));
            acc1 = dot2bf(u1.w, w3, dot2bf(u1.z, w2, dot2bf(u1.y, w1, dot2bf(u1.x, w0, acc1))));
            acc2 = dot2bf(u2.w, w3, dot2bf(u2.z, w2, dot2bf(u2.y, w1, dot2bf(u2.x, w0, acc2))));
            acc3 = dot2bf(u3.w, w3, dot2bf(u3.z, w2, dot2bf(u3.y, w1, dot2bf(u3.x, w0, acc3))));
        }
        xs2[(size_t)n0*64 + lane] = f2bf(acc0);
        xs2[(size_t)n1*64 + lane] = f2bf(acc1);
        xs2[(size_t)n2*64 + lane] = f2bf(acc2);
        xs2[(size_t)n3*64 + lane] = f2bf(acc3);
        #define ARED(ACC, NJ) { \
            float ps = (ACC)*as_w, pd = (ACC)*ad_w; \
            ps += __shfl_xor(ps,1,16); pd += __shfl_xor(pd,1,16); \
            ps += __shfl_xor(ps,2,16); pd += __shfl_xor(pd,2,16); \
            ps += __shfl_xor(ps,4,16); pd += __shfl_xor(pd,4,16); \
            ps += __shfl_xor(ps,8,16); pd += __shfl_xor(pd,8,16); \
            if ((lane & 15) == 0) { \
                a_src4[(NJ)*4 + (lane>>4)] = ps; \
                a_dst4[(NJ)*4 + (lane>>4)] = pd; \
            } }
        ARED(acc0, n0) ARED(acc1, n1) ARED(acc2, n2) ARED(acc3, n3)
        #undef ARED
    }
}

// ---- per layer: GAT, EIGHT nodes per wave via degree-sorted perm ----
// lane = g8*8 + oct; g8 = node slot 0..7, oct = channel octet (head = oct>>1).
// One edge per iteration per node; NO cross-lane reductions anywhere in the
// accumulation (den redundant across the node's 8 lanes).
__global__ __launch_bounds__(256) void k_gat(const uint4* __restrict__ xs4, // [N][8] bf16x8
        const float* __restrict__ a_src4, const float* __restrict__ a_dst4,
        const int* __restrict__ rowptr, const uint2* __restrict__ recs,
        const float4* __restrict__ ea_mean, const int* __restrict__ perm,
        const float* __restrict__ Mc,   // M + l*16   (log2e-scaled)
        const float* __restrict__ c0,   // c0 + l*4   (log2e-scaled)
        const float* __restrict__ bias, const float* __restrict__ lng,
        const float* __restrict__ lnb,
        const ushort* __restrict__ hbf_in, ushort* __restrict__ hbf_out,
        float* __restrict__ out_f32, int last, int n_nodes)
{
    int lane = threadIdx.x & 63;
    int g8 = lane >> 3;        // node slot in wave
    int gq = blockIdx.x*32 + (threadIdx.x >> 6)*8 + g8;
    bool active = (gq < n_nodes);
    int n = active ? perm[gq] : 0;
    int oct = lane & 7;        // channel octet
    int hB  = oct >> 1;        // head owning channels 8*oct..8*oct+7
    int cb = oct * 8;
    uint4 rr = *(const uint4*)(hbf_in + (size_t)n*64 + cb);
    float4 eam = ea_mean[n];
    float m0 = Mc[hB], m1 = Mc[4+hB], m2 = Mc[8+hB], m3 = Mc[12+hB];
    float c0v = c0[hB];
    float adv = a_dst4[n*4 + hB];
    float cc = c0v + adv;
    int rb = rowptr[n], re = active ? rowptr[n + 1] : rb;

    float denL = 0.f;
    float a0=0.f,a1=0.f,a2=0.f,a3=0.f,a4=0.f,a5=0.f,a6=0.f,a7=0.f;

    if (rb < re) {
        int last_e = re - 1;
        uint2 rc = recs[rb];
        int i1 = min(rb + 1, last_e);
        uint2 rn = recs[i1];
        float asc = a_src4[(int)rc.x*4 + hB];
        uint4 xc = xs4[(unsigned)rc.x*8u + (unsigned)oct];
        #pragma unroll 2
        for (int b = rb; b < re; ++b) {
            int i2 = min(b + 2, last_e);
            uint2 r2 = recs[i2];
            float asn = a_src4[(int)rn.x*4 + hB];
            uint4 xn = xs4[(unsigned)rn.x*8u + (unsigned)oct];
            f32x2 e01 = fp8lo(rc.y), e23 = fp8hi(rc.y);
            float al = fmaf(e01.x, m0, fmaf(e01.y, m1,
                       fmaf(e23.x, m2, fmaf(e23.y, m3, cc)))) + asc;
            al = fmaxf(al, LRELU_SLOPE * al);
            float ev = exp2f(al);                      // every iteration is a valid edge
            denL += ev;
            a0 = fmaf(bf_lo(xc.x), ev, a0); a1 = fmaf(bf_hi(xc.x), ev, a1);
            a2 = fmaf(bf_lo(xc.y), ev, a2); a3 = fmaf(bf_hi(xc.y), ev, a3);
            a4 = fmaf(bf_lo(xc.z), ev, a4); a5 = fmaf(bf_hi(xc.z), ev, a5);
            a6 = fmaf(bf_lo(xc.w), ev, a6); a7 = fmaf(bf_hi(xc.w), ev, a7);
            rc = rn; rn = r2; asc = asn; xc = xn;
        }
    }
    // self-loop (edge feature = per-dst mean; exactly 0 if deg==0)
    float ael = (re > rb)
        ? fmaf(eam.x, m0, fmaf(eam.y, m1, fmaf(eam.z, m2, fmaf(eam.w, m3, c0v))))
        : 0.f;
    float alS = a_src4[n*4 + hB] + adv + ael;
    alS = fmaxf(alS, LRELU_SLOPE * alS);
    float evS = exp2f(alS);
    float denF = denL + evS;
    uint4 vs = xs4[(unsigned)n*8u + (unsigned)oct];
    a0 = fmaf(bf_lo(vs.x), evS, a0); a1 = fmaf(bf_hi(vs.x), evS, a1);
    a2 = fmaf(bf_lo(vs.y), evS, a2); a3 = fmaf(bf_hi(vs.y), evS, a3);
    a4 = fmaf(bf_lo(vs.z), evS, a4); a5 = fmaf(bf_hi(vs.z), evS, a5);
    a6 = fmaf(bf_lo(vs.w), evS, a6); a7 = fmaf(bf_hi(vs.w), evS, a7);
    // epilogue: /den + bias + residual(bf16), LayerNorm over 64 ch, ReLU
    float inv = 1.f / (denF + 1e-16f);
    const float4* bp = (const float4*)(bias + cb);
    float4 b0 = bp[0], b1 = bp[1];
    float o0 = a0*inv + b0.x + bf_lo(rr.x), o1 = a1*inv + b0.y + bf_hi(rr.x);
    float o2 = a2*inv + b0.z + bf_lo(rr.y), o3 = a3*inv + b0.w + bf_hi(rr.y);
    float o4 = a4*inv + b1.x + bf_lo(rr.z), o5 = a5*inv + b1.y + bf_hi(rr.z);
    float o6 = a6*inv + b1.z + bf_lo(rr.w), o7 = a7*inv + b1.w + bf_hi(rr.w);
    float s1 = o0+o1+o2+o3+o4+o5+o6+o7;
    s1 += __shfl_xor(s1, 1); s1 += __shfl_xor(s1, 2); s1 += __shfl_xor(s1, 4);
    float mu = s1 * 0.015625f;
    float d0=o0-mu,d1=o1-mu,d2=o2-mu,d3=o3-mu,d4=o4-mu,d5=o5-mu,d6=o6-mu,d7=o7-mu;
    float s2 = d0*d0+d1*d1+d2*d2+d3*d3+d4*d4+d5*d5+d6*d6+d7*d7;
    s2 += __shfl_xor(s2, 1); s2 += __shfl_xor(s2, 2); s2 += __shfl_xor(s2, 4);
    float rs = rsqrtf(s2 * 0.015625f + 1e-5f);
    const float4* gp = (const float4*)(lng + cb);
    const float4* zp = (const float4*)(lnb + cb);
    float4 g0 = gp[0], g1 = gp[1], z0 = zp[0], z1 = zp[1];
    float y0 = fmaxf(d0*rs*g0.x + z0.x, 0.f), y1 = fmaxf(d1*rs*g0.y + z0.y, 0.f);
    float y2 = fmaxf(d2*rs*g0.z + z0.z, 0.f), y3 = fmaxf(d3*rs*g0.w + z0.w, 0.f);
    float y4 = fmaxf(d4*rs*g1.x + z1.x, 0.f), y5 = fmaxf(d5*rs*g1.y + z1.y, 0.f);
    float y6 = fmaxf(d6*rs*g1.z + z1.z, 0.f), y7 = fmaxf(d7*rs*g1.w + z1.w, 0.f);
    if (active) {
        if (last) {
            float4* outp = (float4*)(out_f32 + (size_t)n*64 + cb);
            outp[0] = make_float4(y0, y1, y2, y3);
            outp[1] = make_float4(y4, y5, y6, y7);
        } else {
            uint4 pk;
            pk.x = pack2bf(y0, y1); pk.y = pack2bf(y2, y3);
            pk.z = pack2bf(y4, y5); pk.w = pack2bf(y6, y7);
            *(uint4*)(hbf_out + (size_t)n*64 + cb) = pk;
        }
    }
}

extern "C" void kernel_launch(void* const* d_in, const int* in_sizes, int n_in,
                              void* d_out, int out_size, void* d_ws, size_t ws_size,
                              hipStream_t stream) {
    const float* x          = (const float*)d_in[0];
    const int*   ei         = (const int*)d_in[1];
    const float* edge_attr  = (const float*)d_in[2];
    const float* node_w     = (const float*)d_in[3];
    const float* node_b     = (const float*)d_in[4];
    const float* edge_w     = (const float*)d_in[5];
    const float* edge_b     = (const float*)d_in[6];
    const float* lin_w      = (const float*)d_in[7];
    const float* lin_edge_w = (const float*)d_in[8];
    const float* att_src    = (const float*)d_in[9];
    const float* att_dst    = (const float*)d_in[10];
    const float* att_edge   = (const float*)d_in[11];
    const float* gat_bias   = (const float*)d_in[12];
    const float* ln_g       = (const float*)d_in[13];
    const float* ln_b       = (const float*)d_in[14];

    int NN = in_sizes[0] / 8;
    int E  = in_sizes[1] / 2;
    const int* src = ei;
    const int* dst = ei + E;

    int nbkt = (NN + 255) >> 8;                 // 391 for N=100000 (<= NBKT_MAX)
    int ntot = nbkt * P1B;                      // counter count
    int chunk = (E + P1B - 1) / P1B;

    char* wsp = (char*)d_ws;
    size_t off = 0;
    auto alloc = [&](size_t bytes) -> void* {
        off = (off + 255) & ~(size_t)255;
        void* p = wsp + off;
        off += bytes;
        return p;
    };
    ushort* h_bf    = (ushort*)alloc((size_t)NN * 64 * 2);
    ushort* xs2     = (ushort*)alloc((size_t)NN * 64 * 2);
    float*  a_src4  = (float*)alloc((size_t)NN * 4 * 4);
    float*  a_dst4  = (float*)alloc((size_t)NN * 4 * 4);
    uint2*  recs    = (uint2*)alloc((size_t)E * 8);
    uint2*  brec    = (uint2*)alloc((size_t)E * 8);
    float4* ea_mean = (float4*)alloc((size_t)NN * 16);
    int*    rowptr  = (int*)alloc((size_t)(NN + 1) * 4);
    int*    perm    = (int*)alloc((size_t)NN * 4);
    int*    S       = (int*)alloc((size_t)ntot * 4);
    int*    bsum    = (int*)alloc(4096);
    float*  Mc      = (float*)alloc(256);

    k_prep0<<<1 + (NN*64 + 255) / 256, 256, 0, stream>>>(
        lin_edge_w, att_edge, edge_w, edge_b, Mc, x, node_w, node_b, h_bf, NN);
    k_hist1<<<P1B, 256, 0, stream>>>(dst, S, E, chunk, nbkt);
    int nsb = (ntot + 1023) / 1024;
    k_scanA<<<nsb, 1024, 0, stream>>>(S, S, bsum, ntot);
    k_scanB<<<1, 1024, 0, stream>>>(bsum, nsb);
    k_scat1<<<P1B, 256, 0, stream>>>(dst, src, (const float4*)edge_attr,
                                     S, bsum, brec, E, chunk, nbkt);
    k_csr<<<nbkt, 256, 0, stream>>>(brec, S, bsum, recs, rowptr, perm, nbkt, NN, E);
    k_eamean<<<(NN + 255) / 256, 256, 0, stream>>>(rowptr, recs, ea_mean, NN);

    for (int l = 0; l < 3; ++l) {
        k_proj<<<2048, 256, 0, stream>>>(h_bf, lin_w + l*4096, att_src + l*64,
                                         att_dst + l*64, xs2, a_src4, a_dst4, NN);
        k_gat<<<(NN + 31) / 32, 256, 0, stream>>>((const uint4*)xs2, a_src4, a_dst4,
                                                  rowptr, recs, ea_mean, perm,
                                                  Mc + l*16, Mc + 48 + l*4,
                                                  gat_bias + l*64, ln_g + l*64, ln_b + l*64,
                                                  h_bf, h_bf, (float*)d_out,
                                                  (l == 2) ? 1 : 0, NN);
    }
}

// Round 16
// 352.809 us; speedup vs baseline: 1.0653x; 1.0653x over previous
//
#include <hip/hip_runtime.h>

// GAT encoder, MI355X. Algebraic fold: edge features only enter via the logit
// a_edge = edge_attr(4) @ M[l](4x4) + c0[l](4). CSR-by-dst built ATOMIC-FREE
// (device atomics are serviced memory-side; R8-R10). Bucketing: per-block LDS
// histogram (bin=dst>>8) -> bin-major scan (offsets folded into consumers) ->
// LDS-rank scatter -> per-bucket exact CSR + bucket-local degree-sort perm.
// Edge record = uint2 {src, edge_attr as 4xfp8-e4m3}. Node state h BF16; xs
// bf16. k_gat: FOUR nodes per wave via degree-sorted perm (16-lane quarters,
// 2 edges/chunk). R15 lesson: 8 nodes/wave halves wave count -> MLP-starved
// (VALUBusy 24%); 4/wave keeps N/4 waves for latency hiding while the sort
// removes the max-of-4 degree imbalance (~25% wasted iters in R14).
// Depth-2 pipeline, exp2-domain logits, zero cross-lane ops in hot loop.
// Fused softmax + bias + residual + LN + ReLU.

#define LRELU_SLOPE 0.2f
#define LOG2E 1.4426950408889634f
#define P1B 512            // pass-1 blocks (private ranges per (bin,block))
#define NBKT_MAX 512       // max buckets (N <= 131072)

typedef float f32x2 __attribute__((ext_vector_type(2)));

#ifdef __has_builtin
#if __has_builtin(__builtin_amdgcn_fdot2_f32_bf16)
#define HAS_BF16DOT 1
#endif
#endif
#ifndef HAS_BF16DOT
#define HAS_BF16DOT 0
#endif

#if HAS_BF16DOT
typedef __bf16 bf16x2_t __attribute__((ext_vector_type(2)));
#endif

__device__ __forceinline__ f32x2 fp8lo(unsigned int v) {
    return __builtin_amdgcn_cvt_pk_f32_fp8((int)v, false);
}
__device__ __forceinline__ f32x2 fp8hi(unsigned int v) {
    return __builtin_amdgcn_cvt_pk_f32_fp8((int)v, true);
}
__device__ __forceinline__ ushort f2bf(float x) {
    unsigned int b = __float_as_uint(x);
    return (ushort)((b + 0x7fffu + ((b >> 16) & 1u)) >> 16);   // RNE
}
__device__ __forceinline__ unsigned int pack2bf(float a, float b) {
    return (unsigned int)f2bf(a) | ((unsigned int)f2bf(b) << 16);
}
__device__ __forceinline__ float bf_lo(unsigned int v) { return __uint_as_float(v << 16); }
__device__ __forceinline__ float bf_hi(unsigned int v) { return __uint_as_float(v & 0xffff0000u); }

__device__ __forceinline__ float dot2bf(unsigned int a, unsigned int b, float c) {
#if HAS_BF16DOT
    return __builtin_amdgcn_fdot2_f32_bf16(__builtin_bit_cast(bf16x2_t, a),
                                           __builtin_bit_cast(bf16x2_t, b), c, false);
#else
    return fmaf(bf_lo(a), bf_lo(b), fmaf(bf_hi(a), bf_hi(b), c));
#endif
}

// ---- fused: block 0 = weight folding; blocks 1.. = h0 = x @ node_w + node_b ----
__global__ void k_prep0(const float* __restrict__ lin_edge_w, // [3][64][64]
                        const float* __restrict__ att_edge,   // [3][4][16]
                        const float* __restrict__ edge_w,     // [4][64]
                        const float* __restrict__ edge_b,     // [64]
                        float* __restrict__ Mc,               // [48] M + [12] c0
                        const float* __restrict__ x, const float* __restrict__ nw,
                        const float* __restrict__ nb, ushort* __restrict__ hbf,
                        int n_nodes)
{
    __shared__ float we[3][64][4];
    int t = threadIdx.x;
    if (blockIdx.x == 0) {
        if (t < 192) {
            int l = t >> 6, k = t & 63;
            for (int h = 0; h < 4; ++h) {
                float acc = 0.f;
                #pragma unroll
                for (int c = 0; c < 16; ++c)
                    acc = fmaf(lin_edge_w[l*4096 + k*64 + h*16 + c],
                               att_edge[l*64 + h*16 + c], acc);
                we[l][k][h] = acc;
            }
        }
        __syncthreads();
        if (t < 48) {
            int l = t >> 4, k4 = (t >> 2) & 3, h = t & 3;
            float acc = 0.f;
            for (int k = 0; k < 64; ++k)
                acc = fmaf(edge_w[k4*64 + k], we[l][k][h], acc);
            Mc[l*16 + k4*4 + h] = acc * LOG2E;
        }
        if (t >= 64 && t < 76) {
            int u = t - 64, l = u >> 2, h = u & 3;
            float acc = 0.f;
            for (int k = 0; k < 64; ++k)
                acc = fmaf(edge_b[k], we[l][k][h], acc);
            Mc[48 + l*4 + h] = acc * LOG2E;
        }
        return;
    }
    int idx = (blockIdx.x - 1) * blockDim.x + t;
    int n = idx >> 6, j = idx & 63;
    if (n >= n_nodes) return;
    float acc = nb[j];
    #pragma unroll
    for (int k = 0; k < 8; ++k) acc = fmaf(x[n*8 + k], nw[k*64 + j], acc);
    hbf[(size_t)n*64 + j] = f2bf(acc);
}

// ---- pass 1a: per-block LDS histogram over buckets (bin = dst>>8) ----
__global__ __launch_bounds__(256) void k_hist1(const int* __restrict__ dst,
                                               int* __restrict__ C,
                                               int E, int chunk, int nbkt) {
    __shared__ int h[NBKT_MAX];
    int b = blockIdx.x, t = threadIdx.x;
    for (int i = t; i < nbkt; i += 256) h[i] = 0;
    __syncthreads();
    int e0 = b*chunk, e1 = min(e0 + chunk, E);
    for (int e = e0 + t; e < e1; e += 256)
        atomicAdd(&h[dst[e] >> 8], 1);
    __syncthreads();
    for (int i = t; i < nbkt; i += 256) C[i*P1B + b] = h[i];
}

// ---- scan: per-1024-chunk inclusive (scanA) + block-offset scan (scanB);
//      consumers add bsum[(idx)>>10] themselves (no scanC pass) ----
__global__ void k_scanA(const int* __restrict__ in, int* __restrict__ out,
                        int* __restrict__ bsum, int n) {
    __shared__ int s[1024];
    int i = blockIdx.x*1024 + threadIdx.x;
    s[threadIdx.x] = (i < n) ? in[i] : 0;
    __syncthreads();
    for (int off = 1; off < 1024; off <<= 1) {
        int t = (threadIdx.x >= off) ? s[threadIdx.x - off] : 0;
        __syncthreads();
        s[threadIdx.x] += t;
        __syncthreads();
    }
    if (i < n) out[i] = s[threadIdx.x];               // inclusive chunk scan
    if (threadIdx.x == 1023) bsum[blockIdx.x] = s[1023];
}

__global__ void k_scanB(int* bsum, int nb) {          // nb <= 1024, 1 block
    __shared__ int s[1024];
    int t = threadIdx.x;
    int own = (t < nb) ? bsum[t] : 0;
    s[t] = own;
    __syncthreads();
    for (int off = 1; off < 1024; off <<= 1) {
        int v = (t >= off) ? s[t - off] : 0;
        __syncthreads();
        s[t] += v;
        __syncthreads();
    }
    if (t < nb) bsum[t] = s[t] - own;                 // exclusive block offsets
}

__device__ __forceinline__ int scanned(const int* S, const int* bsum, int idx) {
    return S[idx] + bsum[idx >> 10];                  // full inclusive value
}

// ---- pass 1b: scatter edges into bucket-contiguous staging, LDS ranks only ----
__global__ __launch_bounds__(256) void k_scat1(const int* __restrict__ dst,
        const int* __restrict__ srcv, const float4* __restrict__ ea,
        const int* __restrict__ S, const int* __restrict__ bsum,
        uint2* __restrict__ brec, int E, int chunk, int nbkt) {
    __shared__ int base[NBKT_MAX];
    __shared__ int cur[NBKT_MAX];
    int b = blockIdx.x, t = threadIdx.x;
    for (int i = t; i < nbkt; i += 256) {
        int flat = i*P1B + b;
        base[i] = flat ? scanned(S, bsum, flat - 1) : 0;
        cur[i] = 0;
    }
    __syncthreads();
    int e0 = b*chunk, e1 = min(e0 + chunk, E);
    for (int e = e0 + t; e < e1; e += 256) {
        int d = dst[e];
        int bin = d >> 8;
        int lr = atomicAdd(&cur[bin], 1);             // LDS atomic
        int slot = base[bin] + lr;
        float4 v = ea[e];
        unsigned int p = (unsigned int)__builtin_amdgcn_cvt_pk_fp8_f32(v.x, v.y, 0, false);
        p = (unsigned int)__builtin_amdgcn_cvt_pk_fp8_f32(v.z, v.w, (int)p, true);
        uint2 r;
        r.x = (unsigned int)srcv[e] | ((unsigned int)(d & 255) << 24); // src<2^17
        r.y = p;
        brec[slot] = r;
    }
}

// ---- pass 2: per-bucket exact CSR + bucket-local degree-sort perm ----
__global__ __launch_bounds__(256) void k_csr(const uint2* __restrict__ brec,
        const int* __restrict__ S, const int* __restrict__ bsum,
        uint2* __restrict__ recs, int* __restrict__ rowptr, int* __restrict__ perm,
        int nbkt, int NN, int E) {
    int bkt = blockIdx.x, t = threadIdx.x;
    __shared__ int cnt[256], exc[256], cur[256], ssc[256];
    __shared__ int dh[64], dsc[64], dcu[64];
    int ib = bkt*P1B - 1, ie = (bkt + 1)*P1B - 1;
    int seg_b = bkt ? scanned(S, bsum, ib) : 0;
    int seg_e = scanned(S, bsum, ie);
    cnt[t] = 0; cur[t] = 0;
    if (t < 64) { dh[t] = 0; dcu[t] = 0; }
    __syncthreads();
    for (int i = seg_b + t; i < seg_e; i += 256)
        atomicAdd(&cnt[brec[i].x >> 24], 1);          // LDS atomic
    __syncthreads();
    ssc[t] = cnt[t];
    __syncthreads();
    for (int off = 1; off < 256; off <<= 1) {
        int v = (t >= off) ? ssc[t - off] : 0;
        __syncthreads();
        ssc[t] += v;
        __syncthreads();
    }
    exc[t] = ssc[t] - cnt[t];
    __syncthreads();
    int g = bkt*256 + t;
    bool valid = (g < NN);
    if (valid) rowptr[g] = seg_b + exc[t];            // global CSR offset
    if (bkt == nbkt - 1 && t == 0) rowptr[NN] = E;
    // degree histogram (64 bins, clamp) for bucket-local counting sort
    int dcl = valid ? min(cnt[t], 63) : 0;
    if (valid) atomicAdd(&dh[dcl], 1);
    __syncthreads();
    if (t < 64) dsc[t] = dh[t];
    __syncthreads();
    for (int off = 1; off < 64; off <<= 1) {
        int v = (t >= off && t < 64) ? dsc[t - off] : 0;
        __syncthreads();
        if (t < 64) dsc[t] += v;
        __syncthreads();
    }
    if (valid) {
        int slot = (dsc[dcl] - dh[dcl]) + atomicAdd(&dcu[dcl], 1);
        perm[bkt*256 + slot] = g;                     // degree-sorted within bucket
    }
    // placement pass
    for (int i = seg_b + t; i < seg_e; i += 256) {
        uint2 r = brec[i];
        int dl = (int)(r.x >> 24);
        int slot = seg_b + exc[dl] + atomicAdd(&cur[dl], 1);
        r.x &= 0x00FFFFFFu;
        recs[slot] = r;
    }
}

__global__ void k_eamean(const int* __restrict__ rowptr, const uint2* __restrict__ recs,
                         float4* __restrict__ ea_mean, int n) {
    int i = blockIdx.x*blockDim.x + threadIdx.x;
    if (i >= n) return;
    int b = rowptr[i], e = rowptr[i + 1];
    float sx = 0.f, sy = 0.f, sz = 0.f, sw = 0.f;
    for (int s = b; s < e; ++s) {
        unsigned int p = recs[s].y;
        f32x2 lo = fp8lo(p), hi = fp8hi(p);
        sx += lo.x; sy += lo.y; sz += hi.x; sw += hi.y;
    }
    float inv = (e > b) ? 1.f / (float)(e - b) : 0.f;  // deg=0 -> e_mean = 0
    ea_mean[i] = make_float4(sx*inv, sy*inv, sz*inv, sw*inv);
}

// ---- per layer: xs = h @ lin_w[l] (bf16 in/out, bf16-pair dot); 4 nodes/wave ----
__global__ __launch_bounds__(256) void k_proj(const ushort* __restrict__ hbf,
        const float* __restrict__ lw,   // lin_w + l*4096
        const float* __restrict__ asw,  // att_src + l*64
        const float* __restrict__ adw,  // att_dst + l*64
        ushort* __restrict__ xs2, float* __restrict__ a_src4,
        float* __restrict__ a_dst4, int n_nodes)
{
    __shared__ unsigned int Wp[2048];   // [k2=32][c=64] bf16 pairs (k even/odd)
    for (int i = threadIdx.x; i < 2048; i += 256) {
        int k2 = i >> 6, c = i & 63;
        Wp[i] = pack2bf(lw[(k2*2)*64 + c], lw[(k2*2+1)*64 + c]);
    }
    __syncthreads();
    int lane = threadIdx.x & 63, wid = threadIdx.x >> 6;
    float as_w = asw[lane] * LOG2E, ad_w = adw[lane] * LOG2E;  // exp2-domain logits
    int nquads = (n_nodes + 3) >> 2;
    int nlast = n_nodes - 1;
    for (int q = blockIdx.x*4 + wid; q < nquads; q += gridDim.x*4) {
        int n0 = q << 2;
        int n1 = min(n0+1, nlast), n2 = min(n0+2, nlast), n3 = min(n0+3, nlast);
        const uint4* r0p = (const uint4*)(hbf + (size_t)n0*64);
        const uint4* r1p = (const uint4*)(hbf + (size_t)n1*64);
        const uint4* r2p = (const uint4*)(hbf + (size_t)n2*64);
        const uint4* r3p = (const uint4*)(hbf + (size_t)n3*64);
        float acc0 = 0.f, acc1 = 0.f, acc2 = 0.f, acc3 = 0.f;
        #pragma unroll
        for (int qq = 0; qq < 8; ++qq) {               // 8 x (4 pairs = 8 k)
            uint4 u0 = r0p[qq], u1 = r1p[qq], u2 = r2p[qq], u3 = r3p[qq];
            unsigned int w0 = Wp[(qq*4+0)*64 + lane];
            unsigned int w1 = Wp[(qq*4+1)*64 + lane];
            unsigned int w2 = Wp[(qq*4+2)*64 + lane];
            unsigned int w3 = Wp[(qq*4+3)*64 + lane];
            acc0 = dot2bf(u0.w, w3, dot2bf(u0.z, w2, dot2bf(u0.y, w1, dot2bf(u0.x, w0, acc0))));
            acc1 = dot2bf(u1.w, w3, dot2bf(u1.z, w2, dot2bf(u1.y, w1, dot2bf(u1.x, w0, acc1))));
            acc2 = dot2bf(u2.w, w3, dot2bf(u2.z, w2, dot2bf(u2.y, w1, dot2bf(u2.x, w0, acc2))));
            acc3 = dot2bf(u3.w, w3, dot2bf(u3.z, w2, dot2bf(u3.y, w1, dot2bf(u3.x, w0, acc3))));
        }
        xs2[(size_t)n0*64 + lane] = f2bf(acc0);
        xs2[(size_t)n1*64 + lane] = f2bf(acc1);
        xs2[(size_t)n2*64 + lane] = f2bf(acc2);
        xs2[(size_t)n3*64 + lane] = f2bf(acc3);
        #define ARED(ACC, NJ) { \
            float ps = (ACC)*as_w, pd = (ACC)*ad_w; \
            ps += __shfl_xor(ps,1,16); pd += __shfl_xor(pd,1,16); \
            ps += __shfl_xor(ps,2,16); pd += __shfl_xor(pd,2,16); \
            ps += __shfl_xor(ps,4,16); pd += __shfl_xor(pd,4,16); \
            ps += __shfl_xor(ps,8,16); pd += __shfl_xor(pd,8,16); \
            if ((lane & 15) == 0) { \
                a_src4[(NJ)*4 + (lane>>4)] = ps; \
                a_dst4[(NJ)*4 + (lane>>4)] = pd; \
            } }
        ARED(acc0, n0) ARED(acc1, n1) ARED(acc2, n2) ARED(acc3, n3)
        #undef ARED
    }
}

// ---- per layer: GAT, FOUR nodes/wave via degree-sorted perm (16-lane quarters) ----
// quarter-lane l4 = lane&15 = grp*8 + k8; grp = edge slot (2 edges/chunk),
// k8 = channel octet, head hB = k8>>1. Reduction: xor 8 only (intra-quarter).
__global__ __launch_bounds__(256) void k_gat(const uint4* __restrict__ xs4, // [N][8] bf16x8
        const float* __restrict__ a_src4, const float* __restrict__ a_dst4,
        const int* __restrict__ rowptr, const uint2* __restrict__ recs,
        const float4* __restrict__ ea_mean, const int* __restrict__ perm,
        const float* __restrict__ Mc,   // M + l*16   (log2e-scaled)
        const float* __restrict__ c0,   // c0 + l*4   (log2e-scaled)
        const float* __restrict__ bias, const float* __restrict__ lng,
        const float* __restrict__ lnb,
        const ushort* __restrict__ hbf_in, ushort* __restrict__ hbf_out,
        float* __restrict__ out_f32, int last, int n_nodes)
{
    int lane = threadIdx.x & 63;
    int q4 = lane >> 4;        // quarter 0..3
    int gq = blockIdx.x*16 + (threadIdx.x >> 6)*4 + q4;
    bool active = (gq < n_nodes);
    int n = active ? perm[gq] : 0;
    int l4  = lane & 15;
    int k8  = l4 & 7;          // channel-octet index
    int hB  = k8 >> 1;         // head owning channels 8*k8..8*k8+7
    int grp = l4 >> 3;         // edge slot 0..1 within a chunk
    int cb = k8 * 8;
    uint4 rr = *(const uint4*)(hbf_in + (size_t)n*64 + cb);
    float4 eam = ea_mean[n];
    float m0 = Mc[hB], m1 = Mc[4+hB], m2 = Mc[8+hB], m3 = Mc[12+hB];
    float c0v = c0[hB];
    float adv = a_dst4[n*4 + hB];
    float cc = c0v + adv;
    int rb = rowptr[n], re = active ? rowptr[n + 1] : rb;

    float denL = 0.f;
    float a0=0.f,a1=0.f,a2=0.f,a3=0.f,a4=0.f,a5=0.f,a6=0.f,a7=0.f;

    if (rb < re) {
        int last_e = re - 1;
        int i0 = rb + grp;     i0 = (i0 > last_e) ? last_e : i0;
        uint2 rc = recs[i0];
        int i1 = rb + 2 + grp; i1 = (i1 > last_e) ? last_e : i1;
        uint2 rn = recs[i1];
        float asc = a_src4[(int)rc.x*4 + hB];
        uint4 xc = xs4[(unsigned)rc.x*8u + (unsigned)k8];
        #pragma unroll 2
        for (int b = rb; b < re; b += 2) {
            int i2 = b + 4 + grp; i2 = (i2 > last_e) ? last_e : i2;
            uint2 r2 = recs[i2];
            float asn = a_src4[(int)rn.x*4 + hB];
            uint4 xn = xs4[(unsigned)rn.x*8u + (unsigned)k8];
            f32x2 e01 = fp8lo(rc.y), e23 = fp8hi(rc.y);
            float al = fmaf(e01.x, m0, fmaf(e01.y, m1,
                       fmaf(e23.x, m2, fmaf(e23.y, m3, cc)))) + asc;
            al = fmaxf(al, LRELU_SLOPE * al);
            float ev = (b + grp < re) ? exp2f(al) : 0.f;
            denL += ev;
            a0 = fmaf(bf_lo(xc.x), ev, a0); a1 = fmaf(bf_hi(xc.x), ev, a1);
            a2 = fmaf(bf_lo(xc.y), ev, a2); a3 = fmaf(bf_hi(xc.y), ev, a3);
            a4 = fmaf(bf_lo(xc.z), ev, a4); a5 = fmaf(bf_hi(xc.z), ev, a5);
            a6 = fmaf(bf_lo(xc.w), ev, a6); a7 = fmaf(bf_hi(xc.w), ev, a7);
            rc = rn; rn = r2; asc = asn; xc = xn;
        }
    }
    // reduce den + channel accumulators across the 2 edge slots (intra-quarter)
    denL += __shfl_xor(denL, 8);
    a0 += __shfl_xor(a0, 8); a1 += __shfl_xor(a1, 8);
    a2 += __shfl_xor(a2, 8); a3 += __shfl_xor(a3, 8);
    a4 += __shfl_xor(a4, 8); a5 += __shfl_xor(a5, 8);
    a6 += __shfl_xor(a6, 8); a7 += __shfl_xor(a7, 8);
    // self-loop (edge feature = per-dst mean; exactly 0 if deg==0)
    float ael = (re > rb)
        ? fmaf(eam.x, m0, fmaf(eam.y, m1, fmaf(eam.z, m2, fmaf(eam.w, m3, c0v))))
        : 0.f;
    float alS = a_src4[n*4 + hB] + adv + ael;
    alS = fmaxf(alS, LRELU_SLOPE * alS);
    float evS = exp2f(alS);
    float denF = denL + evS;
    uint4 vs = xs4[(unsigned)n*8u + (unsigned)k8];
    a0 = fmaf(bf_lo(vs.x), evS, a0); a1 = fmaf(bf_hi(vs.x), evS, a1);
    a2 = fmaf(bf_lo(vs.y), evS, a2); a3 = fmaf(bf_hi(vs.y), evS, a3);
    a4 = fmaf(bf_lo(vs.z), evS, a4); a5 = fmaf(bf_hi(vs.z), evS, a5);
    a6 = fmaf(bf_lo(vs.w), evS, a6); a7 = fmaf(bf_hi(vs.w), evS, a7);
    // epilogue: /den + bias + residual(bf16), LayerNorm over 64 ch, ReLU
    float inv = 1.f / (denF + 1e-16f);
    const float4* bp = (const float4*)(bias + cb);
    float4 b0 = bp[0], b1 = bp[1];
    float o0 = a0*inv + b0.x + bf_lo(rr.x), o1 = a1*inv + b0.y + bf_hi(rr.x);
    float o2 = a2*inv + b0.z + bf_lo(rr.y), o3 = a3*inv + b0.w + bf_hi(rr.y);
    float o4 = a4*inv + b1.x + bf_lo(rr.z), o5 = a5*inv + b1.y + bf_hi(rr.z);
    float o6 = a6*inv + b1.z + bf_lo(rr.w), o7 = a7*inv + b1.w + bf_hi(rr.w);
    float s1 = o0+o1+o2+o3+o4+o5+o6+o7;
    s1 += __shfl_xor(s1, 1); s1 += __shfl_xor(s1, 2); s1 += __shfl_xor(s1, 4);
    float mu = s1 * 0.015625f;
    float d0=o0-mu,d1=o1-mu,d2=o2-mu,d3=o3-mu,d4=o4-mu,d5=o5-mu,d6=o6-mu,d7=o7-mu;
    float s2 = d0*d0+d1*d1+d2*d2+d3*d3+d4*d4+d5*d5+d6*d6+d7*d7;
    s2 += __shfl_xor(s2, 1); s2 += __shfl_xor(s2, 2); s2 += __shfl_xor(s2, 4);
    float rs = rsqrtf(s2 * 0.015625f + 1e-5f);
    const float4* gp = (const float4*)(lng + cb);
    const float4* zp = (const float4*)(lnb + cb);
    float4 g0 = gp[0], g1 = gp[1], z0 = zp[0], z1 = zp[1];
    float y0 = fmaxf(d0*rs*g0.x + z0.x, 0.f), y1 = fmaxf(d1*rs*g0.y + z0.y, 0.f);
    float y2 = fmaxf(d2*rs*g0.z + z0.z, 0.f), y3 = fmaxf(d3*rs*g0.w + z0.w, 0.f);
    float y4 = fmaxf(d4*rs*g1.x + z1.x, 0.f), y5 = fmaxf(d5*rs*g1.y + z1.y, 0.f);
    float y6 = fmaxf(d6*rs*g1.z + z1.z, 0.f), y7 = fmaxf(d7*rs*g1.w + z1.w, 0.f);
    if (grp == 0 && active) {
        if (last) {
            float4* outp = (float4*)(out_f32 + (size_t)n*64 + cb);
            outp[0] = make_float4(y0, y1, y2, y3);
            outp[1] = make_float4(y4, y5, y6, y7);
        } else {
            uint4 pk;
            pk.x = pack2bf(y0, y1); pk.y = pack2bf(y2, y3);
            pk.z = pack2bf(y4, y5); pk.w = pack2bf(y6, y7);
            *(uint4*)(hbf_out + (size_t)n*64 + cb) = pk;
        }
    }
}

extern "C" void kernel_launch(void* const* d_in, const int* in_sizes, int n_in,
                              void* d_out, int out_size, void* d_ws, size_t ws_size,
                              hipStream_t stream) {
    const float* x          = (const float*)d_in[0];
    const int*   ei         = (const int*)d_in[1];
    const float* edge_attr  = (const float*)d_in[2];
    const float* node_w     = (const float*)d_in[3];
    const float* node_b     = (const float*)d_in[4];
    const float* edge_w     = (const float*)d_in[5];
    const float* edge_b     = (const float*)d_in[6];
    const float* lin_w      = (const float*)d_in[7];
    const float* lin_edge_w = (const float*)d_in[8];
    const float* att_src    = (const float*)d_in[9];
    const float* att_dst    = (const float*)d_in[10];
    const float* att_edge   = (const float*)d_in[11];
    const float* gat_bias   = (const float*)d_in[12];
    const float* ln_g       = (const float*)d_in[13];
    const float* ln_b       = (const float*)d_in[14];

    int NN = in_sizes[0] / 8;
    int E  = in_sizes[1] / 2;
    const int* src = ei;
    const int* dst = ei + E;

    int nbkt = (NN + 255) >> 8;                 // 391 for N=100000 (<= NBKT_MAX)
    int ntot = nbkt * P1B;                      // counter count
    int chunk = (E + P1B - 1) / P1B;

    char* wsp = (char*)d_ws;
    size_t off = 0;
    auto alloc = [&](size_t bytes) -> void* {
        off = (off + 255) & ~(size_t)255;
        void* p = wsp + off;
        off += bytes;
        return p;
    };
    ushort* h_bf    = (ushort*)alloc((size_t)NN * 64 * 2);
    ushort* xs2     = (ushort*)alloc((size_t)NN * 64 * 2);
    float*  a_src4  = (float*)alloc((size_t)NN * 4 * 4);
    float*  a_dst4  = (float*)alloc((size_t)NN * 4 * 4);
    uint2*  recs    = (uint2*)alloc((size_t)E * 8);
    uint2*  brec    = (uint2*)alloc((size_t)E * 8);
    float4* ea_mean = (float4*)alloc((size_t)NN * 16);
    int*    rowptr  = (int*)alloc((size_t)(NN + 1) * 4);
    int*    perm    = (int*)alloc((size_t)NN * 4);
    int*    S       = (int*)alloc((size_t)ntot * 4);
    int*    bsum    = (int*)alloc(4096);
    float*  Mc      = (float*)alloc(256);

    k_prep0<<<1 + (NN*64 + 255) / 256, 256, 0, stream>>>(
        lin_edge_w, att_edge, edge_w, edge_b, Mc, x, node_w, node_b, h_bf, NN);
    k_hist1<<<P1B, 256, 0, stream>>>(dst, S, E, chunk, nbkt);
    int nsb = (ntot + 1023) / 1024;
    k_scanA<<<nsb, 1024, 0, stream>>>(S, S, bsum, ntot);
    k_scanB<<<1, 1024, 0, stream>>>(bsum, nsb);
    k_scat1<<<P1B, 256, 0, stream>>>(dst, src, (const float4*)edge_attr,
                                     S, bsum, brec, E, chunk, nbkt);
    k_csr<<<nbkt, 256, 0, stream>>>(brec, S, bsum, recs, rowptr, perm, nbkt, NN, E);
    k_eamean<<<(NN + 255) / 256, 256, 0, stream>>>(rowptr, recs, ea_mean, NN);

    for (int l = 0; l < 3; ++l) {
        k_proj<<<2048, 256, 0, stream>>>(h_bf, lin_w + l*4096, att_src + l*64,
                                         att_dst + l*64, xs2, a_src4, a_dst4, NN);
        k_gat<<<(NN + 15) / 16, 256, 0, stream>>>((const uint4*)xs2, a_src4, a_dst4,
                                                  rowptr, recs, ea_mean, perm,
                                                  Mc + l*16, Mc + 48 + l*4,
                                                  gat_bias + l*64, ln_g + l*64, ln_b + l*64,
                                                  h_bf, h_bf, (float*)d_out,
                                                  (l == 2) ? 1 : 0, NN);
    }
}

// Round 17
// 320.068 us; speedup vs baseline: 1.1742x; 1.1023x over previous
//
#include <hip/hip_runtime.h>

// GAT encoder, MI355X. Algebraic fold: edge features only enter via the logit
// a_edge = edge_attr(4) @ M[l](4x4) + c0[l](4). CSR-by-dst built ATOMIC-FREE
// (device atomics are serviced memory-side; R8-R10). Bucketing: per-block LDS
// histogram (bin=dst>>8) -> bin-major scan (offsets folded into consumers) ->
// LDS-rank scatter -> per-bucket exact CSR + WINDOW-16 degree-rank perm.
// R16 lesson: bucket-wide sort scattered co-scheduled nodes (FETCH +12%,
// locality lost, net -20%); window-16 sort keeps the wave's 4 nodes inside one
// 16-node window (CSR ranges ~2KB apart, residuals adjacent) while cutting
// degree-imbalance waste from ~26% to ~12%. Edge record = uint2 {src,
// edge_attr as 4xfp8-e4m3}. Node state h BF16; xs bf16. k_gat: FOUR nodes per
// wave (16-lane quarters, 2 edges/chunk), depth-2 pipeline, exp2-domain
// logits, zero cross-lane ops in hot loop. Fused softmax + bias + residual +
// LN + ReLU.

#define LRELU_SLOPE 0.2f
#define LOG2E 1.4426950408889634f
#define P1B 512            // pass-1 blocks (private ranges per (bin,block))
#define NBKT_MAX 512       // max buckets (N <= 131072)

typedef float f32x2 __attribute__((ext_vector_type(2)));

#ifdef __has_builtin
#if __has_builtin(__builtin_amdgcn_fdot2_f32_bf16)
#define HAS_BF16DOT 1
#endif
#endif
#ifndef HAS_BF16DOT
#define HAS_BF16DOT 0
#endif

#if HAS_BF16DOT
typedef __bf16 bf16x2_t __attribute__((ext_vector_type(2)));
#endif

__device__ __forceinline__ f32x2 fp8lo(unsigned int v) {
    return __builtin_amdgcn_cvt_pk_f32_fp8((int)v, false);
}
__device__ __forceinline__ f32x2 fp8hi(unsigned int v) {
    return __builtin_amdgcn_cvt_pk_f32_fp8((int)v, true);
}
__device__ __forceinline__ ushort f2bf(float x) {
    unsigned int b = __float_as_uint(x);
    return (ushort)((b + 0x7fffu + ((b >> 16) & 1u)) >> 16);   // RNE
}
__device__ __forceinline__ unsigned int pack2bf(float a, float b) {
    return (unsigned int)f2bf(a) | ((unsigned int)f2bf(b) << 16);
}
__device__ __forceinline__ float bf_lo(unsigned int v) { return __uint_as_float(v << 16); }
__device__ __forceinline__ float bf_hi(unsigned int v) { return __uint_as_float(v & 0xffff0000u); }

__device__ __forceinline__ float dot2bf(unsigned int a, unsigned int b, float c) {
#if HAS_BF16DOT
    return __builtin_amdgcn_fdot2_f32_bf16(__builtin_bit_cast(bf16x2_t, a),
                                           __builtin_bit_cast(bf16x2_t, b), c, false);
#else
    return fmaf(bf_lo(a), bf_lo(b), fmaf(bf_hi(a), bf_hi(b), c));
#endif
}

// ---- fused: block 0 = weight folding; blocks 1.. = h0 = x @ node_w + node_b ----
__global__ void k_prep0(const float* __restrict__ lin_edge_w, // [3][64][64]
                        const float* __restrict__ att_edge,   // [3][4][16]
                        const float* __restrict__ edge_w,     // [4][64]
                        const float* __restrict__ edge_b,     // [64]
                        float* __restrict__ Mc,               // [48] M + [12] c0
                        const float* __restrict__ x, const float* __restrict__ nw,
                        const float* __restrict__ nb, ushort* __restrict__ hbf,
                        int n_nodes)
{
    __shared__ float we[3][64][4];
    int t = threadIdx.x;
    if (blockIdx.x == 0) {
        if (t < 192) {
            int l = t >> 6, k = t & 63;
            for (int h = 0; h < 4; ++h) {
                float acc = 0.f;
                #pragma unroll
                for (int c = 0; c < 16; ++c)
                    acc = fmaf(lin_edge_w[l*4096 + k*64 + h*16 + c],
                               att_edge[l*64 + h*16 + c], acc);
                we[l][k][h] = acc;
            }
        }
        __syncthreads();
        if (t < 48) {
            int l = t >> 4, k4 = (t >> 2) & 3, h = t & 3;
            float acc = 0.f;
            for (int k = 0; k < 64; ++k)
                acc = fmaf(edge_w[k4*64 + k], we[l][k][h], acc);
            Mc[l*16 + k4*4 + h] = acc * LOG2E;
        }
        if (t >= 64 && t < 76) {
            int u = t - 64, l = u >> 2, h = u & 3;
            float acc = 0.f;
            for (int k = 0; k < 64; ++k)
                acc = fmaf(edge_b[k], we[l][k][h], acc);
            Mc[48 + l*4 + h] = acc * LOG2E;
        }
        return;
    }
    int idx = (blockIdx.x - 1) * blockDim.x + t;
    int n = idx >> 6, j = idx & 63;
    if (n >= n_nodes) return;
    float acc = nb[j];
    #pragma unroll
    for (int k = 0; k < 8; ++k) acc = fmaf(x[n*8 + k], nw[k*64 + j], acc);
    hbf[(size_t)n*64 + j] = f2bf(acc);
}

// ---- pass 1a: per-block LDS histogram over buckets (bin = dst>>8) ----
__global__ __launch_bounds__(256) void k_hist1(const int* __restrict__ dst,
                                               int* __restrict__ C,
                                               int E, int chunk, int nbkt) {
    __shared__ int h[NBKT_MAX];
    int b = blockIdx.x, t = threadIdx.x;
    for (int i = t; i < nbkt; i += 256) h[i] = 0;
    __syncthreads();
    int e0 = b*chunk, e1 = min(e0 + chunk, E);
    for (int e = e0 + t; e < e1; e += 256)
        atomicAdd(&h[dst[e] >> 8], 1);
    __syncthreads();
    for (int i = t; i < nbkt; i += 256) C[i*P1B + b] = h[i];
}

// ---- scan: per-1024-chunk inclusive (scanA) + block-offset scan (scanB);
//      consumers add bsum[(idx)>>10] themselves (no scanC pass) ----
__global__ void k_scanA(const int* __restrict__ in, int* __restrict__ out,
                        int* __restrict__ bsum, int n) {
    __shared__ int s[1024];
    int i = blockIdx.x*1024 + threadIdx.x;
    s[threadIdx.x] = (i < n) ? in[i] : 0;
    __syncthreads();
    for (int off = 1; off < 1024; off <<= 1) {
        int t = (threadIdx.x >= off) ? s[threadIdx.x - off] : 0;
        __syncthreads();
        s[threadIdx.x] += t;
        __syncthreads();
    }
    if (i < n) out[i] = s[threadIdx.x];               // inclusive chunk scan
    if (threadIdx.x == 1023) bsum[blockIdx.x] = s[1023];
}

__global__ void k_scanB(int* bsum, int nb) {          // nb <= 1024, 1 block
    __shared__ int s[1024];
    int t = threadIdx.x;
    int own = (t < nb) ? bsum[t] : 0;
    s[t] = own;
    __syncthreads();
    for (int off = 1; off < 1024; off <<= 1) {
        int v = (t >= off) ? s[t - off] : 0;
        __syncthreads();
        s[t] += v;
        __syncthreads();
    }
    if (t < nb) bsum[t] = s[t] - own;                 // exclusive block offsets
}

__device__ __forceinline__ int scanned(const int* S, const int* bsum, int idx) {
    return S[idx] + bsum[idx >> 10];                  // full inclusive value
}

// ---- pass 1b: scatter edges into bucket-contiguous staging, LDS ranks only ----
__global__ __launch_bounds__(256) void k_scat1(const int* __restrict__ dst,
        const int* __restrict__ srcv, const float4* __restrict__ ea,
        const int* __restrict__ S, const int* __restrict__ bsum,
        uint2* __restrict__ brec, int E, int chunk, int nbkt) {
    __shared__ int base[NBKT_MAX];
    __shared__ int cur[NBKT_MAX];
    int b = blockIdx.x, t = threadIdx.x;
    for (int i = t; i < nbkt; i += 256) {
        int flat = i*P1B + b;
        base[i] = flat ? scanned(S, bsum, flat - 1) : 0;
        cur[i] = 0;
    }
    __syncthreads();
    int e0 = b*chunk, e1 = min(e0 + chunk, E);
    for (int e = e0 + t; e < e1; e += 256) {
        int d = dst[e];
        int bin = d >> 8;
        int lr = atomicAdd(&cur[bin], 1);             // LDS atomic
        int slot = base[bin] + lr;
        float4 v = ea[e];
        unsigned int p = (unsigned int)__builtin_amdgcn_cvt_pk_fp8_f32(v.x, v.y, 0, false);
        p = (unsigned int)__builtin_amdgcn_cvt_pk_fp8_f32(v.z, v.w, (int)p, true);
        uint2 r;
        r.x = (unsigned int)srcv[e] | ((unsigned int)(d & 255) << 24); // src<2^17
        r.y = p;
        brec[slot] = r;
    }
}

// ---- pass 2: per-bucket exact CSR + WINDOW-16 degree-rank perm ----
__global__ __launch_bounds__(256) void k_csr(const uint2* __restrict__ brec,
        const int* __restrict__ S, const int* __restrict__ bsum,
        uint2* __restrict__ recs, int* __restrict__ rowptr, int* __restrict__ perm,
        int nbkt, int NN, int E) {
    int bkt = blockIdx.x, t = threadIdx.x;
    __shared__ int cnt[256], exc[256], cur[256], ssc[256], dk[256];
    int ib = bkt*P1B - 1, ie = (bkt + 1)*P1B - 1;
    int seg_b = bkt ? scanned(S, bsum, ib) : 0;
    int seg_e = scanned(S, bsum, ie);
    cnt[t] = 0; cur[t] = 0;
    __syncthreads();
    for (int i = seg_b + t; i < seg_e; i += 256)
        atomicAdd(&cnt[brec[i].x >> 24], 1);          // LDS atomic
    __syncthreads();
    ssc[t] = cnt[t];
    __syncthreads();
    for (int off = 1; off < 256; off <<= 1) {
        int v = (t >= off) ? ssc[t - off] : 0;
        __syncthreads();
        ssc[t] += v;
        __syncthreads();
    }
    exc[t] = ssc[t] - cnt[t];
    __syncthreads();
    int g = bkt*256 + t;
    bool valid = (g < NN);
    if (valid) rowptr[g] = seg_b + exc[t];            // global CSR offset
    if (bkt == nbkt - 1 && t == 0) rowptr[NN] = E;
    // window-16 degree rank (invalid nodes sort last -> perm[0..NN-1] valid)
    int myd = valid ? cnt[t] : 0x7FFFFFFF;
    dk[t] = myd;
    __syncthreads();
    int w0 = t & ~15;
    int rank = 0;
    #pragma unroll
    for (int j = 0; j < 16; ++j) {
        int od = dk[w0 + j];
        rank += (int)((od < myd) || (od == myd && (w0 + j) < t));
    }
    perm[bkt*256 + w0 + rank] = g;
    // placement pass
    for (int i = seg_b + t; i < seg_e; i += 256) {
        uint2 r = brec[i];
        int dl = (int)(r.x >> 24);
        int slot = seg_b + exc[dl] + atomicAdd(&cur[dl], 1);
        r.x &= 0x00FFFFFFu;
        recs[slot] = r;
    }
}

__global__ void k_eamean(const int* __restrict__ rowptr, const uint2* __restrict__ recs,
                         float4* __restrict__ ea_mean, int n) {
    int i = blockIdx.x*blockDim.x + threadIdx.x;
    if (i >= n) return;
    int b = rowptr[i], e = rowptr[i + 1];
    float sx = 0.f, sy = 0.f, sz = 0.f, sw = 0.f;
    for (int s = b; s < e; ++s) {
        unsigned int p = recs[s].y;
        f32x2 lo = fp8lo(p), hi = fp8hi(p);
        sx += lo.x; sy += lo.y; sz += hi.x; sw += hi.y;
    }
    float inv = (e > b) ? 1.f / (float)(e - b) : 0.f;  // deg=0 -> e_mean = 0
    ea_mean[i] = make_float4(sx*inv, sy*inv, sz*inv, sw*inv);
}

// ---- per layer: xs = h @ lin_w[l] (bf16 in/out, bf16-pair dot); 4 nodes/wave ----
__global__ __launch_bounds__(256) void k_proj(const ushort* __restrict__ hbf,
        const float* __restrict__ lw,   // lin_w + l*4096
        const float* __restrict__ asw,  // att_src + l*64
        const float* __restrict__ adw,  // att_dst + l*64
        ushort* __restrict__ xs2, float* __restrict__ a_src4,
        float* __restrict__ a_dst4, int n_nodes)
{
    __shared__ unsigned int Wp[2048];   // [k2=32][c=64] bf16 pairs (k even/odd)
    for (int i = threadIdx.x; i < 2048; i += 256) {
        int k2 = i >> 6, c = i & 63;
        Wp[i] = pack2bf(lw[(k2*2)*64 + c], lw[(k2*2+1)*64 + c]);
    }
    __syncthreads();
    int lane = threadIdx.x & 63, wid = threadIdx.x >> 6;
    float as_w = asw[lane] * LOG2E, ad_w = adw[lane] * LOG2E;  // exp2-domain logits
    int nquads = (n_nodes + 3) >> 2;
    int nlast = n_nodes - 1;
    for (int q = blockIdx.x*4 + wid; q < nquads; q += gridDim.x*4) {
        int n0 = q << 2;
        int n1 = min(n0+1, nlast), n2 = min(n0+2, nlast), n3 = min(n0+3, nlast);
        const uint4* r0p = (const uint4*)(hbf + (size_t)n0*64);
        const uint4* r1p = (const uint4*)(hbf + (size_t)n1*64);
        const uint4* r2p = (const uint4*)(hbf + (size_t)n2*64);
        const uint4* r3p = (const uint4*)(hbf + (size_t)n3*64);
        float acc0 = 0.f, acc1 = 0.f, acc2 = 0.f, acc3 = 0.f;
        #pragma unroll
        for (int qq = 0; qq < 8; ++qq) {               // 8 x (4 pairs = 8 k)
            uint4 u0 = r0p[qq], u1 = r1p[qq], u2 = r2p[qq], u3 = r3p[qq];
            unsigned int w0 = Wp[(qq*4+0)*64 + lane];
            unsigned int w1 = Wp[(qq*4+1)*64 + lane];
            unsigned int w2 = Wp[(qq*4+2)*64 + lane];
            unsigned int w3 = Wp[(qq*4+3)*64 + lane];
            acc0 = dot2bf(u0.w, w3, dot2bf(u0.z, w2, dot2bf(u0.y, w1, dot2bf(u0.x, w0, acc0))));
            acc1 = dot2bf(u1.w, w3, dot2bf(u1.z, w2, dot2bf(u1.y, w1, dot2bf(u1.x, w0, acc1))));
            acc2 = dot2bf(u2.w, w3, dot2bf(u2.z, w2, dot2bf(u2.y, w1, dot2bf(u2.x, w0, acc2))));
            acc3 = dot2bf(u3.w, w3, dot2bf(u3.z, w2, dot2bf(u3.y, w1, dot2bf(u3.x, w0, acc3))));
        }
        xs2[(size_t)n0*64 + lane] = f2bf(acc0);
        xs2[(size_t)n1*64 + lane] = f2bf(acc1);
        xs2[(size_t)n2*64 + lane] = f2bf(acc2);
        xs2[(size_t)n3*64 + lane] = f2bf(acc3);
        #define ARED(ACC, NJ) { \
            float ps = (ACC)*as_w, pd = (ACC)*ad_w; \
            ps += __shfl_xor(ps,1,16); pd += __shfl_xor(pd,1,16); \
            ps += __shfl_xor(ps,2,16); pd += __shfl_xor(pd,2,16); \
            ps += __shfl_xor(ps,4,16); pd += __shfl_xor(pd,4,16); \
            ps += __shfl_xor(ps,8,16); pd += __shfl_xor(pd,8,16); \
            if ((lane & 15) == 0) { \
                a_src4[(NJ)*4 + (lane>>4)] = ps; \
                a_dst4[(NJ)*4 + (lane>>4)] = pd; \
            } }
        ARED(acc0, n0) ARED(acc1, n1) ARED(acc2, n2) ARED(acc3, n3)
        #undef ARED
    }
}

// ---- per layer: GAT, FOUR nodes/wave via window-16 perm (16-lane quarters) ----
// quarter-lane l4 = lane&15 = grp*8 + k8; grp = edge slot (2 edges/chunk),
// k8 = channel octet, head hB = k8>>1. Reduction: xor 8 only (intra-quarter).
__global__ __launch_bounds__(256) void k_gat(const uint4* __restrict__ xs4, // [N][8] bf16x8
        const float* __restrict__ a_src4, const float* __restrict__ a_dst4,
        const int* __restrict__ rowptr, const uint2* __restrict__ recs,
        const float4* __restrict__ ea_mean, const int* __restrict__ perm,
        const float* __restrict__ Mc,   // M + l*16   (log2e-scaled)
        const float* __restrict__ c0,   // c0 + l*4   (log2e-scaled)
        const float* __restrict__ bias, const float* __restrict__ lng,
        const float* __restrict__ lnb,
        const ushort* __restrict__ hbf_in, ushort* __restrict__ hbf_out,
        float* __restrict__ out_f32, int last, int n_nodes)
{
    int lane = threadIdx.x & 63;
    int q4 = lane >> 4;        // quarter 0..3
    int gq = blockIdx.x*16 + (threadIdx.x >> 6)*4 + q4;
    bool active = (gq < n_nodes);
    int n = active ? perm[gq] : 0;
    int l4  = lane & 15;
    int k8  = l4 & 7;          // channel-octet index
    int hB  = k8 >> 1;         // head owning channels 8*k8..8*k8+7
    int grp = l4 >> 3;         // edge slot 0..1 within a chunk
    int cb = k8 * 8;
    uint4 rr = *(const uint4*)(hbf_in + (size_t)n*64 + cb);
    float4 eam = ea_mean[n];
    float m0 = Mc[hB], m1 = Mc[4+hB], m2 = Mc[8+hB], m3 = Mc[12+hB];
    float c0v = c0[hB];
    float adv = a_dst4[n*4 + hB];
    float cc = c0v + adv;
    int rb = rowptr[n], re = active ? rowptr[n + 1] : rb;

    float denL = 0.f;
    float a0=0.f,a1=0.f,a2=0.f,a3=0.f,a4=0.f,a5=0.f,a6=0.f,a7=0.f;

    if (rb < re) {
        int last_e = re - 1;
        int i0 = rb + grp;     i0 = (i0 > last_e) ? last_e : i0;
        uint2 rc = recs[i0];
        int i1 = rb + 2 + grp; i1 = (i1 > last_e) ? last_e : i1;
        uint2 rn = recs[i1];
        float asc = a_src4[(int)rc.x*4 + hB];
        uint4 xc = xs4[(unsigned)rc.x*8u + (unsigned)k8];
        #pragma unroll 2
        for (int b = rb; b < re; b += 2) {
            int i2 = b + 4 + grp; i2 = (i2 > last_e) ? last_e : i2;
            uint2 r2 = recs[i2];
            float asn = a_src4[(int)rn.x*4 + hB];
            uint4 xn = xs4[(unsigned)rn.x*8u + (unsigned)k8];
            f32x2 e01 = fp8lo(rc.y), e23 = fp8hi(rc.y);
            float al = fmaf(e01.x, m0, fmaf(e01.y, m1,
                       fmaf(e23.x, m2, fmaf(e23.y, m3, cc)))) + asc;
            al = fmaxf(al, LRELU_SLOPE * al);
            float ev = (b + grp < re) ? exp2f(al) : 0.f;
            denL += ev;
            a0 = fmaf(bf_lo(xc.x), ev, a0); a1 = fmaf(bf_hi(xc.x), ev, a1);
            a2 = fmaf(bf_lo(xc.y), ev, a2); a3 = fmaf(bf_hi(xc.y), ev, a3);
            a4 = fmaf(bf_lo(xc.z), ev, a4); a5 = fmaf(bf_hi(xc.z), ev, a5);
            a6 = fmaf(bf_lo(xc.w), ev, a6); a7 = fmaf(bf_hi(xc.w), ev, a7);
            rc = rn; rn = r2; asc = asn; xc = xn;
        }
    }
    // reduce den + channel accumulators across the 2 edge slots (intra-quarter)
    denL += __shfl_xor(denL, 8);
    a0 += __shfl_xor(a0, 8); a1 += __shfl_xor(a1, 8);
    a2 += __shfl_xor(a2, 8); a3 += __shfl_xor(a3, 8);
    a4 += __shfl_xor(a4, 8); a5 += __shfl_xor(a5, 8);
    a6 += __shfl_xor(a6, 8); a7 += __shfl_xor(a7, 8);
    // self-loop (edge feature = per-dst mean; exactly 0 if deg==0)
    float ael = (re > rb)
        ? fmaf(eam.x, m0, fmaf(eam.y, m1, fmaf(eam.z, m2, fmaf(eam.w, m3, c0v))))
        : 0.f;
    float alS = a_src4[n*4 + hB] + adv + ael;
    alS = fmaxf(alS, LRELU_SLOPE * alS);
    float evS = exp2f(alS);
    float denF = denL + evS;
    uint4 vs = xs4[(unsigned)n*8u + (unsigned)k8];
    a0 = fmaf(bf_lo(vs.x), evS, a0); a1 = fmaf(bf_hi(vs.x), evS, a1);
    a2 = fmaf(bf_lo(vs.y), evS, a2); a3 = fmaf(bf_hi(vs.y), evS, a3);
    a4 = fmaf(bf_lo(vs.z), evS, a4); a5 = fmaf(bf_hi(vs.z), evS, a5);
    a6 = fmaf(bf_lo(vs.w), evS, a6); a7 = fmaf(bf_hi(vs.w), evS, a7);
    // epilogue: /den + bias + residual(bf16), LayerNorm over 64 ch, ReLU
    float inv = 1.f / (denF + 1e-16f);
    const float4* bp = (const float4*)(bias + cb);
    float4 b0 = bp[0], b1 = bp[1];
    float o0 = a0*inv + b0.x + bf_lo(rr.x), o1 = a1*inv + b0.y + bf_hi(rr.x);
    float o2 = a2*inv + b0.z + bf_lo(rr.y), o3 = a3*inv + b0.w + bf_hi(rr.y);
    float o4 = a4*inv + b1.x + bf_lo(rr.z), o5 = a5*inv + b1.y + bf_hi(rr.z);
    float o6 = a6*inv + b1.z + bf_lo(rr.w), o7 = a7*inv + b1.w + bf_hi(rr.w);
    float s1 = o0+o1+o2+o3+o4+o5+o6+o7;
    s1 += __shfl_xor(s1, 1); s1 += __shfl_xor(s1, 2); s1 += __shfl_xor(s1, 4);
    float mu = s1 * 0.015625f;
    float d0=o0-mu,d1=o1-mu,d2=o2-mu,d3=o3-mu,d4=o4-mu,d5=o5-mu,d6=o6-mu,d7=o7-mu;
    float s2 = d0*d0+d1*d1+d2*d2+d3*d3+d4*d4+d5*d5+d6*d6+d7*d7;
    s2 += __shfl_xor(s2, 1); s2 += __shfl_xor(s2, 2); s2 += __shfl_xor(s2, 4);
    float rs = rsqrtf(s2 * 0.015625f + 1e-5f);
    const float4* gp = (const float4*)(lng + cb);
    const float4* zp = (const float4*)(lnb + cb);
    float4 g0 = gp[0], g1 = gp[1], z0 = zp[0], z1 = zp[1];
    float y0 = fmaxf(d0*rs*g0.x + z0.x, 0.f), y1 = fmaxf(d1*rs*g0.y + z0.y, 0.f);
    float y2 = fmaxf(d2*rs*g0.z + z0.z, 0.f), y3 = fmaxf(d3*rs*g0.w + z0.w, 0.f);
    float y4 = fmaxf(d4*rs*g1.x + z1.x, 0.f), y5 = fmaxf(d5*rs*g1.y + z1.y, 0.f);
    float y6 = fmaxf(d6*rs*g1.z + z1.z, 0.f), y7 = fmaxf(d7*rs*g1.w + z1.w, 0.f);
    if (grp == 0 && active) {
        if (last) {
            float4* outp = (float4*)(out_f32 + (size_t)n*64 + cb);
            outp[0] = make_float4(y0, y1, y2, y3);
            outp[1] = make_float4(y4, y5, y6, y7);
        } else {
            uint4 pk;
            pk.x = pack2bf(y0, y1); pk.y = pack2bf(y2, y3);
            pk.z = pack2bf(y4, y5); pk.w = pack2bf(y6, y7);
            *(uint4*)(hbf_out + (size_t)n*64 + cb) = pk;
        }
    }
}

extern "C" void kernel_launch(void* const* d_in, const int* in_sizes, int n_in,
                              void* d_out, int out_size, void* d_ws, size_t ws_size,
                              hipStream_t stream) {
    const float* x          = (const float*)d_in[0];
    const int*   ei         = (const int*)d_in[1];
    const float* edge_attr  = (const float*)d_in[2];
    const float* node_w     = (const float*)d_in[3];
    const float* node_b     = (const float*)d_in[4];
    const float* edge_w     = (const float*)d_in[5];
    const float* edge_b     = (const float*)d_in[6];
    const float* lin_w      = (const float*)d_in[7];
    const float* lin_edge_w = (const float*)d_in[8];
    const float* att_src    = (const float*)d_in[9];
    const float* att_dst    = (const float*)d_in[10];
    const float* att_edge   = (const float*)d_in[11];
    const float* gat_bias   = (const float*)d_in[12];
    const float* ln_g       = (const float*)d_in[13];
    const float* ln_b       = (const float*)d_in[14];

    int NN = in_sizes[0] / 8;
    int E  = in_sizes[1] / 2;
    const int* src = ei;
    const int* dst = ei + E;

    int nbkt = (NN + 255) >> 8;                 // 391 for N=100000 (<= NBKT_MAX)
    int ntot = nbkt * P1B;                      // counter count
    int chunk = (E + P1B - 1) / P1B;

    char* wsp = (char*)d_ws;
    size_t off = 0;
    auto alloc = [&](size_t bytes) -> void* {
        off = (off + 255) & ~(size_t)255;
        void* p = wsp + off;
        off += bytes;
        return p;
    };
    ushort* h_bf    = (ushort*)alloc((size_t)NN * 64 * 2);
    ushort* xs2     = (ushort*)alloc((size_t)NN * 64 * 2);
    float*  a_src4  = (float*)alloc((size_t)NN * 4 * 4);
    float*  a_dst4  = (float*)alloc((size_t)NN * 4 * 4);
    uint2*  recs    = (uint2*)alloc((size_t)E * 8);
    uint2*  brec    = (uint2*)alloc((size_t)E * 8);
    float4* ea_mean = (float4*)alloc((size_t)NN * 16);
    int*    rowptr  = (int*)alloc((size_t)(NN + 1) * 4);
    int*    perm    = (int*)alloc((size_t)(nbkt * 256) * 4);
    int*    S       = (int*)alloc((size_t)ntot * 4);
    int*    bsum    = (int*)alloc(4096);
    float*  Mc      = (float*)alloc(256);

    k_prep0<<<1 + (NN*64 + 255) / 256, 256, 0, stream>>>(
        lin_edge_w, att_edge, edge_w, edge_b, Mc, x, node_w, node_b, h_bf, NN);
    k_hist1<<<P1B, 256, 0, stream>>>(dst, S, E, chunk, nbkt);
    int nsb = (ntot + 1023) / 1024;
    k_scanA<<<nsb, 1024, 0, stream>>>(S, S, bsum, ntot);
    k_scanB<<<1, 1024, 0, stream>>>(bsum, nsb);
    k_scat1<<<P1B, 256, 0, stream>>>(dst, src, (const float4*)edge_attr,
                                     S, bsum, brec, E, chunk, nbkt);
    k_csr<<<nbkt, 256, 0, stream>>>(brec, S, bsum, recs, rowptr, perm, nbkt, NN, E);
    k_eamean<<<(NN + 255) / 256, 256, 0, stream>>>(rowptr, recs, ea_mean, NN);

    for (int l = 0; l < 3; ++l) {
        k_proj<<<2048, 256, 0, stream>>>(h_bf, lin_w + l*4096, att_src + l*64,
                                         att_dst + l*64, xs2, a_src4, a_dst4, NN);
        k_gat<<<(NN + 15) / 16, 256, 0, stream>>>((const uint4*)xs2, a_src4, a_dst4,
                                                  rowptr, recs, ea_mean, perm,
                                                  Mc + l*16, Mc + 48 + l*4,
                                                  gat_bias + l*64, ln_g + l*64, ln_b + l*64,
                                                  h_bf, h_bf, (float*)d_out,
                                                  (l == 2) ? 1 : 0, NN);
    }
}

// Round 18
// 317.671 us; speedup vs baseline: 1.1831x; 1.0075x over previous
//
#include <hip/hip_runtime.h>

// GAT encoder, MI355X. Algebraic fold: edge features only enter via the logit
// a_edge = edge_attr(4) @ M[l](4x4) + c0[l](4). CSR-by-dst built ATOMIC-FREE
// (device atomics are serviced memory-side; R8-R10). Bucketing: per-block LDS
// histogram (bin=dst>>8) -> bin-major scan (offsets folded into consumers) ->
// LDS-rank scatter -> per-bucket exact CSR + WINDOW-16 degree-rank perm +
// FUSED ea_mean (phase 3 reads the bucket's just-written L2-hot recs) +
// 8 sentinel pad records after recs[E] (k_gat prefetch needs no clamping).
// Edge record = uint2 {src, edge_attr as 4xfp8-e4m3}. Node state h BF16; xs
// bf16. k_gat: FOUR nodes per wave via window-16 perm (16-lane quarters,
// 2 edges/chunk), depth-2 pipeline, exp2-domain logits, zero cross-lane ops
// in hot loop, clamp-free prefetch. Fused softmax + bias + residual + LN +
// ReLU. k_gat is fetch-service-bound (~2.9 TB/s on random 128B rows).

#define LRELU_SLOPE 0.2f
#define LOG2E 1.4426950408889634f
#define P1B 512            // pass-1 blocks (private ranges per (bin,block))
#define NBKT_MAX 512       // max buckets (N <= 131072)

typedef float f32x2 __attribute__((ext_vector_type(2)));

#ifdef __has_builtin
#if __has_builtin(__builtin_amdgcn_fdot2_f32_bf16)
#define HAS_BF16DOT 1
#endif
#endif
#ifndef HAS_BF16DOT
#define HAS_BF16DOT 0
#endif

#if HAS_BF16DOT
typedef __bf16 bf16x2_t __attribute__((ext_vector_type(2)));
#endif

__device__ __forceinline__ f32x2 fp8lo(unsigned int v) {
    return __builtin_amdgcn_cvt_pk_f32_fp8((int)v, false);
}
__device__ __forceinline__ f32x2 fp8hi(unsigned int v) {
    return __builtin_amdgcn_cvt_pk_f32_fp8((int)v, true);
}
__device__ __forceinline__ ushort f2bf(float x) {
    unsigned int b = __float_as_uint(x);
    return (ushort)((b + 0x7fffu + ((b >> 16) & 1u)) >> 16);   // RNE
}
__device__ __forceinline__ unsigned int pack2bf(float a, float b) {
    return (unsigned int)f2bf(a) | ((unsigned int)f2bf(b) << 16);
}
__device__ __forceinline__ float bf_lo(unsigned int v) { return __uint_as_float(v << 16); }
__device__ __forceinline__ float bf_hi(unsigned int v) { return __uint_as_float(v & 0xffff0000u); }

__device__ __forceinline__ float dot2bf(unsigned int a, unsigned int b, float c) {
#if HAS_BF16DOT
    return __builtin_amdgcn_fdot2_f32_bf16(__builtin_bit_cast(bf16x2_t, a),
                                           __builtin_bit_cast(bf16x2_t, b), c, false);
#else
    return fmaf(bf_lo(a), bf_lo(b), fmaf(bf_hi(a), bf_hi(b), c));
#endif
}

// ---- fused: block 0 = weight folding; blocks 1.. = h0 = x @ node_w + node_b ----
__global__ void k_prep0(const float* __restrict__ lin_edge_w, // [3][64][64]
                        const float* __restrict__ att_edge,   // [3][4][16]
                        const float* __restrict__ edge_w,     // [4][64]
                        const float* __restrict__ edge_b,     // [64]
                        float* __restrict__ Mc,               // [48] M + [12] c0
                        const float* __restrict__ x, const float* __restrict__ nw,
                        const float* __restrict__ nb, ushort* __restrict__ hbf,
                        int n_nodes)
{
    __shared__ float we[3][64][4];
    int t = threadIdx.x;
    if (blockIdx.x == 0) {
        if (t < 192) {
            int l = t >> 6, k = t & 63;
            for (int h = 0; h < 4; ++h) {
                float acc = 0.f;
                #pragma unroll
                for (int c = 0; c < 16; ++c)
                    acc = fmaf(lin_edge_w[l*4096 + k*64 + h*16 + c],
                               att_edge[l*64 + h*16 + c], acc);
                we[l][k][h] = acc;
            }
        }
        __syncthreads();
        if (t < 48) {
            int l = t >> 4, k4 = (t >> 2) & 3, h = t & 3;
            float acc = 0.f;
            for (int k = 0; k < 64; ++k)
                acc = fmaf(edge_w[k4*64 + k], we[l][k][h], acc);
            Mc[l*16 + k4*4 + h] = acc * LOG2E;
        }
        if (t >= 64 && t < 76) {
            int u = t - 64, l = u >> 2, h = u & 3;
            float acc = 0.f;
            for (int k = 0; k < 64; ++k)
                acc = fmaf(edge_b[k], we[l][k][h], acc);
            Mc[48 + l*4 + h] = acc * LOG2E;
        }
        return;
    }
    int idx = (blockIdx.x - 1) * blockDim.x + t;
    int n = idx >> 6, j = idx & 63;
    if (n >= n_nodes) return;
    float acc = nb[j];
    #pragma unroll
    for (int k = 0; k < 8; ++k) acc = fmaf(x[n*8 + k], nw[k*64 + j], acc);
    hbf[(size_t)n*64 + j] = f2bf(acc);
}

// ---- pass 1a: per-block LDS histogram over buckets (bin = dst>>8) ----
__global__ __launch_bounds__(256) void k_hist1(const int* __restrict__ dst,
                                               int* __restrict__ C,
                                               int E, int chunk, int nbkt) {
    __shared__ int h[NBKT_MAX];
    int b = blockIdx.x, t = threadIdx.x;
    for (int i = t; i < nbkt; i += 256) h[i] = 0;
    __syncthreads();
    int e0 = b*chunk, e1 = min(e0 + chunk, E);
    for (int e = e0 + t; e < e1; e += 256)
        atomicAdd(&h[dst[e] >> 8], 1);
    __syncthreads();
    for (int i = t; i < nbkt; i += 256) C[i*P1B + b] = h[i];
}

// ---- scan: per-1024-chunk inclusive (scanA) + block-offset scan (scanB);
//      consumers add bsum[(idx)>>10] themselves (no scanC pass) ----
__global__ void k_scanA(const int* __restrict__ in, int* __restrict__ out,
                        int* __restrict__ bsum, int n) {
    __shared__ int s[1024];
    int i = blockIdx.x*1024 + threadIdx.x;
    s[threadIdx.x] = (i < n) ? in[i] : 0;
    __syncthreads();
    for (int off = 1; off < 1024; off <<= 1) {
        int t = (threadIdx.x >= off) ? s[threadIdx.x - off] : 0;
        __syncthreads();
        s[threadIdx.x] += t;
        __syncthreads();
    }
    if (i < n) out[i] = s[threadIdx.x];               // inclusive chunk scan
    if (threadIdx.x == 1023) bsum[blockIdx.x] = s[1023];
}

__global__ void k_scanB(int* bsum, int nb) {          // nb <= 1024, 1 block
    __shared__ int s[1024];
    int t = threadIdx.x;
    int own = (t < nb) ? bsum[t] : 0;
    s[t] = own;
    __syncthreads();
    for (int off = 1; off < 1024; off <<= 1) {
        int v = (t >= off) ? s[t - off] : 0;
        __syncthreads();
        s[t] += v;
        __syncthreads();
    }
    if (t < nb) bsum[t] = s[t] - own;                 // exclusive block offsets
}

__device__ __forceinline__ int scanned(const int* S, const int* bsum, int idx) {
    return S[idx] + bsum[idx >> 10];                  // full inclusive value
}

// ---- pass 1b: scatter edges into bucket-contiguous staging, LDS ranks only ----
__global__ __launch_bounds__(256) void k_scat1(const int* __restrict__ dst,
        const int* __restrict__ srcv, const float4* __restrict__ ea,
        const int* __restrict__ S, const int* __restrict__ bsum,
        uint2* __restrict__ brec, int E, int chunk, int nbkt) {
    __shared__ int base[NBKT_MAX];
    __shared__ int cur[NBKT_MAX];
    int b = blockIdx.x, t = threadIdx.x;
    for (int i = t; i < nbkt; i += 256) {
        int flat = i*P1B + b;
        base[i] = flat ? scanned(S, bsum, flat - 1) : 0;
        cur[i] = 0;
    }
    __syncthreads();
    int e0 = b*chunk, e1 = min(e0 + chunk, E);
    for (int e = e0 + t; e < e1; e += 256) {
        int d = dst[e];
        int bin = d >> 8;
        int lr = atomicAdd(&cur[bin], 1);             // LDS atomic
        int slot = base[bin] + lr;
        float4 v = ea[e];
        unsigned int p = (unsigned int)__builtin_amdgcn_cvt_pk_fp8_f32(v.x, v.y, 0, false);
        p = (unsigned int)__builtin_amdgcn_cvt_pk_fp8_f32(v.z, v.w, (int)p, true);
        uint2 r;
        r.x = (unsigned int)srcv[e] | ((unsigned int)(d & 255) << 24); // src<2^17
        r.y = p;
        brec[slot] = r;
    }
}

// ---- pass 2: per-bucket exact CSR + window-16 degree-rank perm + fused
//      ea_mean (phase 3: re-read the bucket's L2-hot recs) + sentinel pad ----
__global__ __launch_bounds__(256) void k_csr(const uint2* __restrict__ brec,
        const int* __restrict__ S, const int* __restrict__ bsum,
        uint2* __restrict__ recs, int* __restrict__ rowptr, int* __restrict__ perm,
        float4* __restrict__ ea_mean, int nbkt, int NN, int E) {
    int bkt = blockIdx.x, t = threadIdx.x;
    __shared__ int cnt[256], exc[256], cur[256], ssc[256], dk[256];
    int ib = bkt*P1B - 1, ie = (bkt + 1)*P1B - 1;
    int seg_b = bkt ? scanned(S, bsum, ib) : 0;
    int seg_e = scanned(S, bsum, ie);
    cnt[t] = 0; cur[t] = 0;
    __syncthreads();
    for (int i = seg_b + t; i < seg_e; i += 256)
        atomicAdd(&cnt[brec[i].x >> 24], 1);          // LDS atomic
    __syncthreads();
    ssc[t] = cnt[t];
    __syncthreads();
    for (int off = 1; off < 256; off <<= 1) {
        int v = (t >= off) ? ssc[t - off] : 0;
        __syncthreads();
        ssc[t] += v;
        __syncthreads();
    }
    exc[t] = ssc[t] - cnt[t];
    __syncthreads();
    int g = bkt*256 + t;
    bool valid = (g < NN);
    int row_b = seg_b + exc[t];
    if (valid) rowptr[g] = row_b;                     // global CSR offset
    if (bkt == nbkt - 1 && t == 0) rowptr[NN] = E;
    // window-16 degree rank (invalid nodes sort last -> perm[0..NN-1] valid)
    int myd = valid ? cnt[t] : 0x7FFFFFFF;
    dk[t] = myd;
    __syncthreads();
    int w0 = t & ~15;
    int rank = 0;
    #pragma unroll
    for (int j = 0; j < 16; ++j) {
        int od = dk[w0 + j];
        rank += (int)((od < myd) || (od == myd && (w0 + j) < t));
    }
    perm[bkt*256 + w0 + rank] = g;
    // placement pass
    for (int i = seg_b + t; i < seg_e; i += 256) {
        uint2 r = brec[i];
        int dl = (int)(r.x >> 24);
        int slot = seg_b + exc[dl] + atomicAdd(&cur[dl], 1);
        r.x &= 0x00FFFFFFu;
        recs[slot] = r;
    }
    __syncthreads();                                  // recs visible block-wide
    // phase 3: fused ea_mean (sequential read of own node's L2-hot edges)
    if (valid) {
        int deg = cnt[t];
        float sx = 0.f, sy = 0.f, sz = 0.f, sw = 0.f;
        for (int i = 0; i < deg; ++i) {
            unsigned int p = recs[row_b + i].y;
            f32x2 lo = fp8lo(p), hi = fp8hi(p);
            sx += lo.x; sy += lo.y; sz += hi.x; sw += hi.y;
        }
        float inv = deg ? 1.f / (float)deg : 0.f;     // deg=0 -> e_mean = 0
        ea_mean[g] = make_float4(sx*inv, sy*inv, sz*inv, sw*inv);
    }
    // sentinel pad so k_gat's prefetch never reads past valid records
    if (bkt == nbkt - 1 && t < 8 && E > 0) recs[E + t] = recs[E - 1];
}

// ---- per layer: xs = h @ lin_w[l] (bf16 in/out, bf16-pair dot); 4 nodes/wave ----
__global__ __launch_bounds__(256) void k_proj(const ushort* __restrict__ hbf,
        const float* __restrict__ lw,   // lin_w + l*4096
        const float* __restrict__ asw,  // att_src + l*64
        const float* __restrict__ adw,  // att_dst + l*64
        ushort* __restrict__ xs2, float* __restrict__ a_src4,
        float* __restrict__ a_dst4, int n_nodes)
{
    __shared__ unsigned int Wp[2048];   // [k2=32][c=64] bf16 pairs (k even/odd)
    for (int i = threadIdx.x; i < 2048; i += 256) {
        int k2 = i >> 6, c = i & 63;
        Wp[i] = pack2bf(lw[(k2*2)*64 + c], lw[(k2*2+1)*64 + c]);
    }
    __syncthreads();
    int lane = threadIdx.x & 63, wid = threadIdx.x >> 6;
    float as_w = asw[lane] * LOG2E, ad_w = adw[lane] * LOG2E;  // exp2-domain logits
    int nquads = (n_nodes + 3) >> 2;
    int nlast = n_nodes - 1;
    for (int q = blockIdx.x*4 + wid; q < nquads; q += gridDim.x*4) {
        int n0 = q << 2;
        int n1 = min(n0+1, nlast), n2 = min(n0+2, nlast), n3 = min(n0+3, nlast);
        const uint4* r0p = (const uint4*)(hbf + (size_t)n0*64);
        const uint4* r1p = (const uint4*)(hbf + (size_t)n1*64);
        const uint4* r2p = (const uint4*)(hbf + (size_t)n2*64);
        const uint4* r3p = (const uint4*)(hbf + (size_t)n3*64);
        float acc0 = 0.f, acc1 = 0.f, acc2 = 0.f, acc3 = 0.f;
        #pragma unroll
        for (int qq = 0; qq < 8; ++qq) {               // 8 x (4 pairs = 8 k)
            uint4 u0 = r0p[qq], u1 = r1p[qq], u2 = r2p[qq], u3 = r3p[qq];
            unsigned int w0 = Wp[(qq*4+0)*64 + lane];
            unsigned int w1 = Wp[(qq*4+1)*64 + lane];
            unsigned int w2 = Wp[(qq*4+2)*64 + lane];
            unsigned int w3 = Wp[(qq*4+3)*64 + lane];
            acc0 = dot2bf(u0.w, w3, dot2bf(u0.z, w2, dot2bf(u0.y, w1, dot2bf(u0.x, w0, acc0))));
            acc1 = dot2bf(u1.w, w3, dot2bf(u1.z, w2, dot2bf(u1.y, w1, dot2bf(u1.x, w0, acc1))));
            acc2 = dot2bf(u2.w, w3, dot2bf(u2.z, w2, dot2bf(u2.y, w1, dot2bf(u2.x, w0, acc2))));
            acc3 = dot2bf(u3.w, w3, dot2bf(u3.z, w2, dot2bf(u3.y, w1, dot2bf(u3.x, w0, acc3))));
        }
        xs2[(size_t)n0*64 + lane] = f2bf(acc0);
        xs2[(size_t)n1*64 + lane] = f2bf(acc1);
        xs2[(size_t)n2*64 + lane] = f2bf(acc2);
        xs2[(size_t)n3*64 + lane] = f2bf(acc3);
        #define ARED(ACC, NJ) { \
            float ps = (ACC)*as_w, pd = (ACC)*ad_w; \
            ps += __shfl_xor(ps,1,16); pd += __shfl_xor(pd,1,16); \
            ps += __shfl_xor(ps,2,16); pd += __shfl_xor(pd,2,16); \
            ps += __shfl_xor(ps,4,16); pd += __shfl_xor(pd,4,16); \
            ps += __shfl_xor(ps,8,16); pd += __shfl_xor(pd,8,16); \
            if ((lane & 15) == 0) { \
                a_src4[(NJ)*4 + (lane>>4)] = ps; \
                a_dst4[(NJ)*4 + (lane>>4)] = pd; \
            } }
        ARED(acc0, n0) ARED(acc1, n1) ARED(acc2, n2) ARED(acc3, n3)
        #undef ARED
    }
}

// ---- per layer: GAT, FOUR nodes/wave via window-16 perm (16-lane quarters) ----
// quarter-lane l4 = lane&15 = grp*8 + k8; grp = edge slot (2 edges/chunk),
// k8 = channel octet, head hB = k8>>1. Clamp-free prefetch (recs padded +8).
__global__ __launch_bounds__(256) void k_gat(const uint4* __restrict__ xs4, // [N][8] bf16x8
        const float* __restrict__ a_src4, const float* __restrict__ a_dst4,
        const int* __restrict__ rowptr, const uint2* __restrict__ recs,
        const float4* __restrict__ ea_mean, const int* __restrict__ perm,
        const float* __restrict__ Mc,   // M + l*16   (log2e-scaled)
        const float* __restrict__ c0,   // c0 + l*4   (log2e-scaled)
        const float* __restrict__ bias, const float* __restrict__ lng,
        const float* __restrict__ lnb,
        const ushort* __restrict__ hbf_in, ushort* __restrict__ hbf_out,
        float* __restrict__ out_f32, int last, int n_nodes)
{
    int lane = threadIdx.x & 63;
    int q4 = lane >> 4;        // quarter 0..3
    int gq = blockIdx.x*16 + (threadIdx.x >> 6)*4 + q4;
    bool active = (gq < n_nodes);
    int n = active ? perm[gq] : 0;
    int l4  = lane & 15;
    int k8  = l4 & 7;          // channel-octet index
    int hB  = k8 >> 1;         // head owning channels 8*k8..8*k8+7
    int grp = l4 >> 3;         // edge slot 0..1 within a chunk
    int cb = k8 * 8;
    uint4 rr = *(const uint4*)(hbf_in + (size_t)n*64 + cb);
    float4 eam = ea_mean[n];
    float m0 = Mc[hB], m1 = Mc[4+hB], m2 = Mc[8+hB], m3 = Mc[12+hB];
    float c0v = c0[hB];
    float adv = a_dst4[n*4 + hB];
    float cc = c0v + adv;
    int rb = rowptr[n], re = active ? rowptr[n + 1] : rb;

    float denL = 0.f;
    float a0=0.f,a1=0.f,a2=0.f,a3=0.f,a4=0.f,a5=0.f,a6=0.f,a7=0.f;

    if (rb < re) {
        int bmax = re - grp;                          // mask base (hoisted)
        uint2 rc = recs[rb + grp];
        uint2 rn = recs[rb + 2 + grp];
        float asc = a_src4[(int)rc.x*4 + hB];
        uint4 xc = xs4[(unsigned)rc.x*8u + (unsigned)k8];
        #pragma unroll 2
        for (int b = rb; b < re; b += 2) {
            uint2 r2 = recs[b + 4 + grp];             // clamp-free (padded)
            float asn = a_src4[(int)rn.x*4 + hB];
            uint4 xn = xs4[(unsigned)rn.x*8u + (unsigned)k8];
            f32x2 e01 = fp8lo(rc.y), e23 = fp8hi(rc.y);
            float al = fmaf(e01.x, m0, fmaf(e01.y, m1,
                       fmaf(e23.x, m2, fmaf(e23.y, m3, cc)))) + asc;
            al = fmaxf(al, LRELU_SLOPE * al);
            float ev = (b < bmax) ? exp2f(al) : 0.f;
            denL += ev;
            a0 = fmaf(bf_lo(xc.x), ev, a0); a1 = fmaf(bf_hi(xc.x), ev, a1);
            a2 = fmaf(bf_lo(xc.y), ev, a2); a3 = fmaf(bf_hi(xc.y), ev, a3);
            a4 = fmaf(bf_lo(xc.z), ev, a4); a5 = fmaf(bf_hi(xc.z), ev, a5);
            a6 = fmaf(bf_lo(xc.w), ev, a6); a7 = fmaf(bf_hi(xc.w), ev, a7);
            rc = rn; rn = r2; asc = asn; xc = xn;
        }
    }
    // reduce den + channel accumulators across the 2 edge slots (intra-quarter)
    denL += __shfl_xor(denL, 8);
    a0 += __shfl_xor(a0, 8); a1 += __shfl_xor(a1, 8);
    a2 += __shfl_xor(a2, 8); a3 += __shfl_xor(a3, 8);
    a4 += __shfl_xor(a4, 8); a5 += __shfl_xor(a5, 8);
    a6 += __shfl_xor(a6, 8); a7 += __shfl_xor(a7, 8);
    // self-loop (edge feature = per-dst mean; exactly 0 if deg==0)
    float ael = (re > rb)
        ? fmaf(eam.x, m0, fmaf(eam.y, m1, fmaf(eam.z, m2, fmaf(eam.w, m3, c0v))))
        : 0.f;
    float alS = a_src4[n*4 + hB] + adv + ael;
    alS = fmaxf(alS, LRELU_SLOPE * alS);
    float evS = exp2f(alS);
    float denF = denL + evS;
    uint4 vs = xs4[(unsigned)n*8u + (unsigned)k8];
    a0 = fmaf(bf_lo(vs.x), evS, a0); a1 = fmaf(bf_hi(vs.x), evS, a1);
    a2 = fmaf(bf_lo(vs.y), evS, a2); a3 = fmaf(bf_hi(vs.y), evS, a3);
    a4 = fmaf(bf_lo(vs.z), evS, a4); a5 = fmaf(bf_hi(vs.z), evS, a5);
    a6 = fmaf(bf_lo(vs.w), evS, a6); a7 = fmaf(bf_hi(vs.w), evS, a7);
    // epilogue: /den + bias + residual(bf16), LayerNorm over 64 ch, ReLU
    float inv = 1.f / (denF + 1e-16f);
    const float4* bp = (const float4*)(bias + cb);
    float4 b0 = bp[0], b1 = bp[1];
    float o0 = a0*inv + b0.x + bf_lo(rr.x), o1 = a1*inv + b0.y + bf_hi(rr.x);
    float o2 = a2*inv + b0.z + bf_lo(rr.y), o3 = a3*inv + b0.w + bf_hi(rr.y);
    float o4 = a4*inv + b1.x + bf_lo(rr.z), o5 = a5*inv + b1.y + bf_hi(rr.z);
    float o6 = a6*inv + b1.z + bf_lo(rr.w), o7 = a7*inv + b1.w + bf_hi(rr.w);
    float s1 = o0+o1+o2+o3+o4+o5+o6+o7;
    s1 += __shfl_xor(s1, 1); s1 += __shfl_xor(s1, 2); s1 += __shfl_xor(s1, 4);
    float mu = s1 * 0.015625f;
    float d0=o0-mu,d1=o1-mu,d2=o2-mu,d3=o3-mu,d4=o4-mu,d5=o5-mu,d6=o6-mu,d7=o7-mu;
    float s2 = d0*d0+d1*d1+d2*d2+d3*d3+d4*d4+d5*d5+d6*d6+d7*d7;
    s2 += __shfl_xor(s2, 1); s2 += __shfl_xor(s2, 2); s2 += __shfl_xor(s2, 4);
    float rs = rsqrtf(s2 * 0.015625f + 1e-5f);
    const float4* gp = (const float4*)(lng + cb);
    const float4* zp = (const float4*)(lnb + cb);
    float4 g0 = gp[0], g1 = gp[1], z0 = zp[0], z1 = zp[1];
    float y0 = fmaxf(d0*rs*g0.x + z0.x, 0.f), y1 = fmaxf(d1*rs*g0.y + z0.y, 0.f);
    float y2 = fmaxf(d2*rs*g0.z + z0.z, 0.f), y3 = fmaxf(d3*rs*g0.w + z0.w, 0.f);
    float y4 = fmaxf(d4*rs*g1.x + z1.x, 0.f), y5 = fmaxf(d5*rs*g1.y + z1.y, 0.f);
    float y6 = fmaxf(d6*rs*g1.z + z1.z, 0.f), y7 = fmaxf(d7*rs*g1.w + z1.w, 0.f);
    if (grp == 0 && active) {
        if (last) {
            float4* outp = (float4*)(out_f32 + (size_t)n*64 + cb);
            outp[0] = make_float4(y0, y1, y2, y3);
            outp[1] = make_float4(y4, y5, y6, y7);
        } else {
            uint4 pk;
            pk.x = pack2bf(y0, y1); pk.y = pack2bf(y2, y3);
            pk.z = pack2bf(y4, y5); pk.w = pack2bf(y6, y7);
            *(uint4*)(hbf_out + (size_t)n*64 + cb) = pk;
        }
    }
}

extern "C" void kernel_launch(void* const* d_in, const int* in_sizes, int n_in,
                              void* d_out, int out_size, void* d_ws, size_t ws_size,
                              hipStream_t stream) {
    const float* x          = (const float*)d_in[0];
    const int*   ei         = (const int*)d_in[1];
    const float* edge_attr  = (const float*)d_in[2];
    const float* node_w     = (const float*)d_in[3];
    const float* node_b     = (const float*)d_in[4];
    const float* edge_w     = (const float*)d_in[5];
    const float* edge_b     = (const float*)d_in[6];
    const float* lin_w      = (const float*)d_in[7];
    const float* lin_edge_w = (const float*)d_in[8];
    const float* att_src    = (const float*)d_in[9];
    const float* att_dst    = (const float*)d_in[10];
    const float* att_edge   = (const float*)d_in[11];
    const float* gat_bias   = (const float*)d_in[12];
    const float* ln_g       = (const float*)d_in[13];
    const float* ln_b       = (const float*)d_in[14];

    int NN = in_sizes[0] / 8;
    int E  = in_sizes[1] / 2;
    const int* src = ei;
    const int* dst = ei + E;

    int nbkt = (NN + 255) >> 8;                 // 391 for N=100000 (<= NBKT_MAX)
    int ntot = nbkt * P1B;                      // counter count
    int chunk = (E + P1B - 1) / P1B;

    char* wsp = (char*)d_ws;
    size_t off = 0;
    auto alloc = [&](size_t bytes) -> void* {
        off = (off + 255) & ~(size_t)255;
        void* p = wsp + off;
        off += bytes;
        return p;
    };
    ushort* h_bf    = (ushort*)alloc((size_t)NN * 64 * 2);
    ushort* xs2     = (ushort*)alloc((size_t)NN * 64 * 2);
    float*  a_src4  = (float*)alloc((size_t)NN * 4 * 4);
    float*  a_dst4  = (float*)alloc((size_t)NN * 4 * 4);
    uint2*  recs    = (uint2*)alloc((size_t)(E + 8) * 8);  // +8 sentinel pad
    uint2*  brec    = (uint2*)alloc((size_t)E * 8);
    float4* ea_mean = (float4*)alloc((size_t)NN * 16);
    int*    rowptr  = (int*)alloc((size_t)(NN + 1) * 4);
    int*    perm    = (int*)alloc((size_t)(nbkt * 256) * 4);
    int*    S       = (int*)alloc((size_t)ntot * 4);
    int*    bsum    = (int*)alloc(4096);
    float*  Mc      = (float*)alloc(256);

    k_prep0<<<1 + (NN*64 + 255) / 256, 256, 0, stream>>>(
        lin_edge_w, att_edge, edge_w, edge_b, Mc, x, node_w, node_b, h_bf, NN);
    k_hist1<<<P1B, 256, 0, stream>>>(dst, S, E, chunk, nbkt);
    int nsb = (ntot + 1023) / 1024;
    k_scanA<<<nsb, 1024, 0, stream>>>(S, S, bsum, ntot);
    k_scanB<<<1, 1024, 0, stream>>>(bsum, nsb);
    k_scat1<<<P1B, 256, 0, stream>>>(dst, src, (const float4*)edge_attr,
                                     S, bsum, brec, E, chunk, nbkt);
    k_csr<<<nbkt, 256, 0, stream>>>(brec, S, bsum, recs, rowptr, perm, ea_mean,
                                    nbkt, NN, E);

    for (int l = 0; l < 3; ++l) {
        k_proj<<<2048, 256, 0, stream>>>(h_bf, lin_w + l*4096, att_src + l*64,
                                         att_dst + l*64, xs2, a_src4, a_dst4, NN);
        k_gat<<<(NN + 15) / 16, 256, 0, stream>>>((const uint4*)xs2, a_src4, a_dst4,
                                                  rowptr, recs, ea_mean, perm,
                                                  Mc + l*16, Mc + 48 + l*4,
                                                  gat_bias + l*64, ln_g + l*64, ln_b + l*64,
                                                  h_bf, h_bf, (float*)d_out,
                                                  (l == 2) ? 1 : 0, NN);
    }
}

// Round 19
// 303.585 us; speedup vs baseline: 1.2380x; 1.0464x over previous
//
#include <hip/hip_runtime.h>

// GAT encoder, MI355X. Algebraic fold: edge features only enter via the logit
// a_edge = edge_attr(4) @ M[l](4x4) + c0[l](4). CSR-by-dst built ATOMIC-FREE.
// Bucketing: per-block LDS histogram (bin=dst>>8, FUSED into prep0) ->
// bin-major scan -> LDS-rank scatter -> per-bucket exact CSR + window-16
// degree-rank perm + fused ea_mean + sentinel pad (+ FUSED layer-0 proj in
// the same dispatch, disjoint block range). Edge record = uint2 {src,
// edge_attr as 4xfp8-e4m3}. Node state h BF16; xs bf16. k_gat: FOUR nodes
// per wave via window-16 perm (16-lane quarters, 2 edges/chunk), DEPTH-3
// pipeline (xs/a_src gathers issued 4 edges ahead), exp2-domain logits,
// clamp-free prefetch. Fused softmax + bias + residual + LN + ReLU.

#define LRELU_SLOPE 0.2f
#define LOG2E 1.4426950408889634f
#define P1B 512            // pass-1 blocks (private ranges per (bin,block))
#define NBKT_MAX 512       // max buckets (N <= 131072)
#define PROJB 2048         // proj block count (fused + standalone)

typedef float f32x2 __attribute__((ext_vector_type(2)));

#ifdef __has_builtin
#if __has_builtin(__builtin_amdgcn_fdot2_f32_bf16)
#define HAS_BF16DOT 1
#endif
#endif
#ifndef HAS_BF16DOT
#define HAS_BF16DOT 0
#endif

#if HAS_BF16DOT
typedef __bf16 bf16x2_t __attribute__((ext_vector_type(2)));
#endif

__device__ __forceinline__ f32x2 fp8lo(unsigned int v) {
    return __builtin_amdgcn_cvt_pk_f32_fp8((int)v, false);
}
__device__ __forceinline__ f32x2 fp8hi(unsigned int v) {
    return __builtin_amdgcn_cvt_pk_f32_fp8((int)v, true);
}
__device__ __forceinline__ ushort f2bf(float x) {
    unsigned int b = __float_as_uint(x);
    return (ushort)((b + 0x7fffu + ((b >> 16) & 1u)) >> 16);   // RNE
}
__device__ __forceinline__ unsigned int pack2bf(float a, float b) {
    return (unsigned int)f2bf(a) | ((unsigned int)f2bf(b) << 16);
}
__device__ __forceinline__ float bf_lo(unsigned int v) { return __uint_as_float(v << 16); }
__device__ __forceinline__ float bf_hi(unsigned int v) { return __uint_as_float(v & 0xffff0000u); }

__device__ __forceinline__ float dot2bf(unsigned int a, unsigned int b, float c) {
#if HAS_BF16DOT
    return __builtin_amdgcn_fdot2_f32_bf16(__builtin_bit_cast(bf16x2_t, a),
                                           __builtin_bit_cast(bf16x2_t, b), c, false);
#else
    return fmaf(bf_lo(a), bf_lo(b), fmaf(bf_hi(a), bf_hi(b), c));
#endif
}

// ---- shared proj body (used by fused layer-0 and standalone layers 1,2) ----
__device__ __forceinline__ void proj_body(int pb, int t,
        const ushort* __restrict__ hbf, const float* __restrict__ lw,
        const float* __restrict__ asw, const float* __restrict__ adw,
        ushort* __restrict__ xs2, float* __restrict__ a_src4,
        float* __restrict__ a_dst4, int n_nodes, unsigned int* Wp)
{
    for (int i = t; i < 2048; i += 256) {
        int k2 = i >> 6, c = i & 63;
        Wp[i] = pack2bf(lw[(k2*2)*64 + c], lw[(k2*2+1)*64 + c]);
    }
    __syncthreads();
    int lane = t & 63, wid = t >> 6;
    float as_w = asw[lane] * LOG2E, ad_w = adw[lane] * LOG2E;  // exp2-domain
    int nquads = (n_nodes + 3) >> 2;
    int nlast = n_nodes - 1;
    for (int q = pb*4 + wid; q < nquads; q += PROJB*4) {
        int n0 = q << 2;
        int n1 = min(n0+1, nlast), n2 = min(n0+2, nlast), n3 = min(n0+3, nlast);
        const uint4* r0p = (const uint4*)(hbf + (size_t)n0*64);
        const uint4* r1p = (const uint4*)(hbf + (size_t)n1*64);
        const uint4* r2p = (const uint4*)(hbf + (size_t)n2*64);
        const uint4* r3p = (const uint4*)(hbf + (size_t)n3*64);
        float acc0 = 0.f, acc1 = 0.f, acc2 = 0.f, acc3 = 0.f;
        #pragma unroll
        for (int qq = 0; qq < 8; ++qq) {               // 8 x (4 pairs = 8 k)
            uint4 u0 = r0p[qq], u1 = r1p[qq], u2 = r2p[qq], u3 = r3p[qq];
            unsigned int w0 = Wp[(qq*4+0)*64 + lane];
            unsigned int w1 = Wp[(qq*4+1)*64 + lane];
            unsigned int w2 = Wp[(qq*4+2)*64 + lane];
            unsigned int w3 = Wp[(qq*4+3)*64 + lane];
            acc0 = dot2bf(u0.w, w3, dot2bf(u0.z, w2, dot2bf(u0.y, w1, dot2bf(u0.x, w0, acc0))));
            acc1 = dot2bf(u1.w, w3, dot2bf(u1.z, w2, dot2bf(u1.y, w1, dot2bf(u1.x, w0, acc1))));
            acc2 = dot2bf(u2.w, w3, dot2bf(u2.z, w2, dot2bf(u2.y, w1, dot2bf(u2.x, w0, acc2))));
            acc3 = dot2bf(u3.w, w3, dot2bf(u3.z, w2, dot2bf(u3.y, w1, dot2bf(u3.x, w0, acc3))));
        }
        xs2[(size_t)n0*64 + lane] = f2bf(acc0);
        xs2[(size_t)n1*64 + lane] = f2bf(acc1);
        xs2[(size_t)n2*64 + lane] = f2bf(acc2);
        xs2[(size_t)n3*64 + lane] = f2bf(acc3);
        #define ARED(ACC, NJ) { \
            float ps = (ACC)*as_w, pd = (ACC)*ad_w; \
            ps += __shfl_xor(ps,1,16); pd += __shfl_xor(pd,1,16); \
            ps += __shfl_xor(ps,2,16); pd += __shfl_xor(pd,2,16); \
            ps += __shfl_xor(ps,4,16); pd += __shfl_xor(pd,4,16); \
            ps += __shfl_xor(ps,8,16); pd += __shfl_xor(pd,8,16); \
            if ((lane & 15) == 0) { \
                a_src4[(NJ)*4 + (lane>>4)] = ps; \
                a_dst4[(NJ)*4 + (lane>>4)] = pd; \
            } }
        ARED(acc0, n0) ARED(acc1, n1) ARED(acc2, n2) ARED(acc3, n3)
        #undef ARED
    }
}

// ---- fused: block 0 = weight fold; 1..P1B = bucket histogram; rest = h0 ----
__global__ __launch_bounds__(256) void k_prep0(const float* __restrict__ lin_edge_w,
                        const float* __restrict__ att_edge,
                        const float* __restrict__ edge_w,
                        const float* __restrict__ edge_b,
                        float* __restrict__ Mc,
                        const float* __restrict__ x, const float* __restrict__ nw,
                        const float* __restrict__ nb, ushort* __restrict__ hbf,
                        const int* __restrict__ dst, int* __restrict__ C,
                        int E, int chunk, int nbkt, int n_nodes)
{
    __shared__ float we[3][64][4];
    __shared__ int hh[NBKT_MAX];
    int t = threadIdx.x;
    if (blockIdx.x == 0) {
        if (t < 192) {
            int l = t >> 6, k = t & 63;
            for (int h = 0; h < 4; ++h) {
                float acc = 0.f;
                #pragma unroll
                for (int c = 0; c < 16; ++c)
                    acc = fmaf(lin_edge_w[l*4096 + k*64 + h*16 + c],
                               att_edge[l*64 + h*16 + c], acc);
                we[l][k][h] = acc;
            }
        }
        __syncthreads();
        if (t < 48) {
            int l = t >> 4, k4 = (t >> 2) & 3, h = t & 3;
            float acc = 0.f;
            for (int k = 0; k < 64; ++k)
                acc = fmaf(edge_w[k4*64 + k], we[l][k][h], acc);
            Mc[l*16 + k4*4 + h] = acc * LOG2E;
        }
        if (t >= 64 && t < 76) {
            int u = t - 64, l = u >> 2, h = u & 3;
            float acc = 0.f;
            for (int k = 0; k < 64; ++k)
                acc = fmaf(edge_b[k], we[l][k][h], acc);
            Mc[48 + l*4 + h] = acc * LOG2E;
        }
        return;
    }
    if (blockIdx.x <= P1B) {                          // histogram blocks
        int b = blockIdx.x - 1;
        for (int i = t; i < nbkt; i += 256) hh[i] = 0;
        __syncthreads();
        int e0 = b*chunk, e1 = min(e0 + chunk, E);
        for (int e = e0 + t; e < e1; e += 256)
            atomicAdd(&hh[dst[e] >> 8], 1);
        __syncthreads();
        for (int i = t; i < nbkt; i += 256) C[i*P1B + b] = hh[i];
        return;
    }
    int idx = (blockIdx.x - 1 - P1B) * 256 + t;       // node-proj blocks
    int n = idx >> 6, j = idx & 63;
    if (n >= n_nodes) return;
    float acc = nb[j];
    #pragma unroll
    for (int k = 0; k < 8; ++k) acc = fmaf(x[n*8 + k], nw[k*64 + j], acc);
    hbf[(size_t)n*64 + j] = f2bf(acc);
}

// ---- scan chain (offsets folded into consumers) ----
__global__ void k_scanA(const int* __restrict__ in, int* __restrict__ out,
                        int* __restrict__ bsum, int n) {
    __shared__ int s[1024];
    int i = blockIdx.x*1024 + threadIdx.x;
    s[threadIdx.x] = (i < n) ? in[i] : 0;
    __syncthreads();
    for (int off = 1; off < 1024; off <<= 1) {
        int t = (threadIdx.x >= off) ? s[threadIdx.x - off] : 0;
        __syncthreads();
        s[threadIdx.x] += t;
        __syncthreads();
    }
    if (i < n) out[i] = s[threadIdx.x];               // inclusive chunk scan
    if (threadIdx.x == 1023) bsum[blockIdx.x] = s[1023];
}

__global__ void k_scanB(int* bsum, int nb) {          // nb <= 1024, 1 block
    __shared__ int s[1024];
    int t = threadIdx.x;
    int own = (t < nb) ? bsum[t] : 0;
    s[t] = own;
    __syncthreads();
    for (int off = 1; off < 1024; off <<= 1) {
        int v = (t >= off) ? s[t - off] : 0;
        __syncthreads();
        s[t] += v;
        __syncthreads();
    }
    if (t < nb) bsum[t] = s[t] - own;                 // exclusive block offsets
}

__device__ __forceinline__ int scanned(const int* S, const int* bsum, int idx) {
    return S[idx] + bsum[idx >> 10];                  // full inclusive value
}

// ---- pass 1b: scatter edges into bucket-contiguous staging, LDS ranks only ----
__global__ __launch_bounds__(256) void k_scat1(const int* __restrict__ dst,
        const int* __restrict__ srcv, const float4* __restrict__ ea,
        const int* __restrict__ S, const int* __restrict__ bsum,
        uint2* __restrict__ brec, int E, int chunk, int nbkt) {
    __shared__ int base[NBKT_MAX];
    __shared__ int cur[NBKT_MAX];
    int b = blockIdx.x, t = threadIdx.x;
    for (int i = t; i < nbkt; i += 256) {
        int flat = i*P1B + b;
        base[i] = flat ? scanned(S, bsum, flat - 1) : 0;
        cur[i] = 0;
    }
    __syncthreads();
    int e0 = b*chunk, e1 = min(e0 + chunk, E);
    for (int e = e0 + t; e < e1; e += 256) {
        int d = dst[e];
        int bin = d >> 8;
        int lr = atomicAdd(&cur[bin], 1);             // LDS atomic
        int slot = base[bin] + lr;
        float4 v = ea[e];
        unsigned int p = (unsigned int)__builtin_amdgcn_cvt_pk_fp8_f32(v.x, v.y, 0, false);
        p = (unsigned int)__builtin_amdgcn_cvt_pk_fp8_f32(v.z, v.w, (int)p, true);
        uint2 r;
        r.x = (unsigned int)srcv[e] | ((unsigned int)(d & 255) << 24); // src<2^17
        r.y = p;
        brec[slot] = r;
    }
}

// ---- pass 2 (blocks 0..nbkt-1): per-bucket exact CSR + window-16 perm +
//      fused ea_mean + sentinel pad; (blocks nbkt..): layer-0 proj ----
__global__ __launch_bounds__(256) void k_csrproj(const uint2* __restrict__ brec,
        const int* __restrict__ S, const int* __restrict__ bsum,
        uint2* __restrict__ recs, int* __restrict__ rowptr, int* __restrict__ perm,
        float4* __restrict__ ea_mean, int nbkt, int NN, int E,
        const ushort* __restrict__ hbf, const float* __restrict__ lw,
        const float* __restrict__ asw, const float* __restrict__ adw,
        ushort* __restrict__ xs2, float* __restrict__ a_src4,
        float* __restrict__ a_dst4)
{
    __shared__ int cnt[256], exc[256], cur[256], ssc[256], dk[256];
    __shared__ unsigned int Wp[2048];
    int t = threadIdx.x;
    if (blockIdx.x >= nbkt) {                         // layer-0 proj blocks
        proj_body(blockIdx.x - nbkt, t, hbf, lw, asw, adw,
                  xs2, a_src4, a_dst4, NN, Wp);
        return;
    }
    int bkt = blockIdx.x;
    int ib = bkt*P1B - 1, ie = (bkt + 1)*P1B - 1;
    int seg_b = bkt ? scanned(S, bsum, ib) : 0;
    int seg_e = scanned(S, bsum, ie);
    cnt[t] = 0; cur[t] = 0;
    __syncthreads();
    for (int i = seg_b + t; i < seg_e; i += 256)
        atomicAdd(&cnt[brec[i].x >> 24], 1);          // LDS atomic
    __syncthreads();
    ssc[t] = cnt[t];
    __syncthreads();
    for (int off = 1; off < 256; off <<= 1) {
        int v = (t >= off) ? ssc[t - off] : 0;
        __syncthreads();
        ssc[t] += v;
        __syncthreads();
    }
    exc[t] = ssc[t] - cnt[t];
    __syncthreads();
    int g = bkt*256 + t;
    bool valid = (g < NN);
    int row_b = seg_b + exc[t];
    if (valid) rowptr[g] = row_b;                     // global CSR offset
    if (bkt == nbkt - 1 && t == 0) rowptr[NN] = E;
    // window-16 degree rank (invalid nodes sort last -> perm[0..NN-1] valid)
    int myd = valid ? cnt[t] : 0x7FFFFFFF;
    dk[t] = myd;
    __syncthreads();
    int w0 = t & ~15;
    int rank = 0;
    #pragma unroll
    for (int j = 0; j < 16; ++j) {
        int od = dk[w0 + j];
        rank += (int)((od < myd) || (od == myd && (w0 + j) < t));
    }
    perm[bkt*256 + w0 + rank] = g;
    // placement pass
    for (int i = seg_b + t; i < seg_e; i += 256) {
        uint2 r = brec[i];
        int dl = (int)(r.x >> 24);
        int slot = seg_b + exc[dl] + atomicAdd(&cur[dl], 1);
        r.x &= 0x00FFFFFFu;
        recs[slot] = r;
    }
    __syncthreads();                                  // recs visible block-wide
    // fused ea_mean (sequential read of own node's L2-hot edges)
    if (valid) {
        int deg = cnt[t];
        float sx = 0.f, sy = 0.f, sz = 0.f, sw = 0.f;
        for (int i = 0; i < deg; ++i) {
            unsigned int p = recs[row_b + i].y;
            f32x2 lo = fp8lo(p), hi = fp8hi(p);
            sx += lo.x; sy += lo.y; sz += hi.x; sw += hi.y;
        }
        float inv = deg ? 1.f / (float)deg : 0.f;     // deg=0 -> e_mean = 0
        ea_mean[g] = make_float4(sx*inv, sy*inv, sz*inv, sw*inv);
    }
    // sentinel pad so k_gat's prefetch never reads past valid records
    if (bkt == nbkt - 1 && t < 8 && E > 0) recs[E + t] = recs[E - 1];
}

// ---- standalone proj (layers 1,2) ----
__global__ __launch_bounds__(256) void k_proj(const ushort* __restrict__ hbf,
        const float* __restrict__ lw, const float* __restrict__ asw,
        const float* __restrict__ adw, ushort* __restrict__ xs2,
        float* __restrict__ a_src4, float* __restrict__ a_dst4, int n_nodes)
{
    __shared__ unsigned int Wp[2048];
    proj_body(blockIdx.x, threadIdx.x, hbf, lw, asw, adw,
              xs2, a_src4, a_dst4, n_nodes, Wp);
}

// ---- per layer: GAT, FOUR nodes/wave via window-16 perm, DEPTH-3 pipeline ----
// quarter-lane l4 = lane&15 = grp*8 + k8; grp = edge slot (2 edges/chunk),
// k8 = channel octet, head hB = k8>>1. Clamp-free prefetch (recs padded +8).
__global__ __launch_bounds__(256) void k_gat(const uint4* __restrict__ xs4, // [N][8] bf16x8
        const float* __restrict__ a_src4, const float* __restrict__ a_dst4,
        const int* __restrict__ rowptr, const uint2* __restrict__ recs,
        const float4* __restrict__ ea_mean, const int* __restrict__ perm,
        const float* __restrict__ Mc,   // M + l*16   (log2e-scaled)
        const float* __restrict__ c0,   // c0 + l*4   (log2e-scaled)
        const float* __restrict__ bias, const float* __restrict__ lng,
        const float* __restrict__ lnb,
        const ushort* __restrict__ hbf_in, ushort* __restrict__ hbf_out,
        float* __restrict__ out_f32, int last, int n_nodes)
{
    int lane = threadIdx.x & 63;
    int q4 = lane >> 4;        // quarter 0..3
    int gq = blockIdx.x*16 + (threadIdx.x >> 6)*4 + q4;
    bool active = (gq < n_nodes);
    int n = active ? perm[gq] : 0;
    int l4  = lane & 15;
    int k8  = l4 & 7;          // channel-octet index
    int hB  = k8 >> 1;         // head owning channels 8*k8..8*k8+7
    int grp = l4 >> 3;         // edge slot 0..1 within a chunk
    int cb = k8 * 8;
    uint4 rr = *(const uint4*)(hbf_in + (size_t)n*64 + cb);
    float4 eam = ea_mean[n];
    float m0 = Mc[hB], m1 = Mc[4+hB], m2 = Mc[8+hB], m3 = Mc[12+hB];
    float c0v = c0[hB];
    float adv = a_dst4[n*4 + hB];
    float cc = c0v + adv;
    int rb = rowptr[n], re = active ? rowptr[n + 1] : rb;

    float denL = 0.f;
    float a0=0.f,a1=0.f,a2=0.f,a3=0.f,a4=0.f,a5=0.f,a6=0.f,a7=0.f;

    if (rb < re) {
        int bmax = re - grp;                          // mask base (hoisted)
        uint2 rc = recs[rb + grp];
        uint2 rn = recs[rb + 2 + grp];
        uint2 r2 = recs[rb + 4 + grp];
        float asc = a_src4[(int)rc.x*4 + hB];
        float asn = a_src4[(int)rn.x*4 + hB];
        uint4 xc = xs4[(unsigned)rc.x*8u + (unsigned)k8];
        uint4 xn = xs4[(unsigned)rn.x*8u + (unsigned)k8];
        #pragma unroll 2
        for (int b = rb; b < re; b += 2) {
            uint2 r3 = recs[b + 6 + grp];             // clamp-free (padded)
            float as2 = a_src4[(int)r2.x*4 + hB];
            uint4 x2 = xs4[(unsigned)r2.x*8u + (unsigned)k8];
            f32x2 e01 = fp8lo(rc.y), e23 = fp8hi(rc.y);
            float al = fmaf(e01.x, m0, fmaf(e01.y, m1,
                       fmaf(e23.x, m2, fmaf(e23.y, m3, cc)))) + asc;
            al = fmaxf(al, LRELU_SLOPE * al);
            float ev = (b < bmax) ? exp2f(al) : 0.f;
            denL += ev;
            a0 = fmaf(bf_lo(xc.x), ev, a0); a1 = fmaf(bf_hi(xc.x), ev, a1);
            a2 = fmaf(bf_lo(xc.y), ev, a2); a3 = fmaf(bf_hi(xc.y), ev, a3);
            a4 = fmaf(bf_lo(xc.z), ev, a4); a5 = fmaf(bf_hi(xc.z), ev, a5);
            a6 = fmaf(bf_lo(xc.w), ev, a6); a7 = fmaf(bf_hi(xc.w), ev, a7);
            rc = rn; rn = r2; r2 = r3;
            asc = asn; asn = as2;
            xc = xn; xn = x2;
        }
    }
    // reduce den + channel accumulators across the 2 edge slots (intra-quarter)
    denL += __shfl_xor(denL, 8);
    a0 += __shfl_xor(a0, 8); a1 += __shfl_xor(a1, 8);
    a2 += __shfl_xor(a2, 8); a3 += __shfl_xor(a3, 8);
    a4 += __shfl_xor(a4, 8); a5 += __shfl_xor(a5, 8);
    a6 += __shfl_xor(a6, 8); a7 += __shfl_xor(a7, 8);
    // self-loop (edge feature = per-dst mean; exactly 0 if deg==0)
    float ael = (re > rb)
        ? fmaf(eam.x, m0, fmaf(eam.y, m1, fmaf(eam.z, m2, fmaf(eam.w, m3, c0v))))
        : 0.f;
    float alS = a_src4[n*4 + hB] + adv + ael;
    alS = fmaxf(alS, LRELU_SLOPE * alS);
    float evS = exp2f(alS);
    float denF = denL + evS;
    uint4 vs = xs4[(unsigned)n*8u + (unsigned)k8];
    a0 = fmaf(bf_lo(vs.x), evS, a0); a1 = fmaf(bf_hi(vs.x), evS, a1);
    a2 = fmaf(bf_lo(vs.y), evS, a2); a3 = fmaf(bf_hi(vs.y), evS, a3);
    a4 = fmaf(bf_lo(vs.z), evS, a4); a5 = fmaf(bf_hi(vs.z), evS, a5);
    a6 = fmaf(bf_lo(vs.w), evS, a6); a7 = fmaf(bf_hi(vs.w), evS, a7);
    // epilogue: /den + bias + residual(bf16), LayerNorm over 64 ch, ReLU
    float inv = 1.f / (denF + 1e-16f);
    const float4* bp = (const float4*)(bias + cb);
    float4 b0 = bp[0], b1 = bp[1];
    float o0 = a0*inv + b0.x + bf_lo(rr.x), o1 = a1*inv + b0.y + bf_hi(rr.x);
    float o2 = a2*inv + b0.z + bf_lo(rr.y), o3 = a3*inv + b0.w + bf_hi(rr.y);
    float o4 = a4*inv + b1.x + bf_lo(rr.z), o5 = a5*inv + b1.y + bf_hi(rr.z);
    float o6 = a6*inv + b1.z + bf_lo(rr.w), o7 = a7*inv + b1.w + bf_hi(rr.w);
    float s1 = o0+o1+o2+o3+o4+o5+o6+o7;
    s1 += __shfl_xor(s1, 1); s1 += __shfl_xor(s1, 2); s1 += __shfl_xor(s1, 4);
    float mu = s1 * 0.015625f;
    float d0=o0-mu,d1=o1-mu,d2=o2-mu,d3=o3-mu,d4=o4-mu,d5=o5-mu,d6=o6-mu,d7=o7-mu;
    float s2 = d0*d0+d1*d1+d2*d2+d3*d3+d4*d4+d5*d5+d6*d6+d7*d7;
    s2 += __shfl_xor(s2, 1); s2 += __shfl_xor(s2, 2); s2 += __shfl_xor(s2, 4);
    float rs = rsqrtf(s2 * 0.015625f + 1e-5f);
    const float4* gp = (const float4*)(lng + cb);
    const float4* zp = (const float4*)(lnb + cb);
    float4 g0 = gp[0], g1 = gp[1], z0 = zp[0], z1 = zp[1];
    float y0 = fmaxf(d0*rs*g0.x + z0.x, 0.f), y1 = fmaxf(d1*rs*g0.y + z0.y, 0.f);
    float y2 = fmaxf(d2*rs*g0.z + z0.z, 0.f), y3 = fmaxf(d3*rs*g0.w + z0.w, 0.f);
    float y4 = fmaxf(d4*rs*g1.x + z1.x, 0.f), y5 = fmaxf(d5*rs*g1.y + z1.y, 0.f);
    float y6 = fmaxf(d6*rs*g1.z + z1.z, 0.f), y7 = fmaxf(d7*rs*g1.w + z1.w, 0.f);
    if (grp == 0 && active) {
        if (last) {
            float4* outp = (float4*)(out_f32 + (size_t)n*64 + cb);
            outp[0] = make_float4(y0, y1, y2, y3);
            outp[1] = make_float4(y4, y5, y6, y7);
        } else {
            uint4 pk;
            pk.x = pack2bf(y0, y1); pk.y = pack2bf(y2, y3);
            pk.z = pack2bf(y4, y5); pk.w = pack2bf(y6, y7);
            *(uint4*)(hbf_out + (size_t)n*64 + cb) = pk;
        }
    }
}

extern "C" void kernel_launch(void* const* d_in, const int* in_sizes, int n_in,
                              void* d_out, int out_size, void* d_ws, size_t ws_size,
                              hipStream_t stream) {
    const float* x          = (const float*)d_in[0];
    const int*   ei         = (const int*)d_in[1];
    const float* edge_attr  = (const float*)d_in[2];
    const float* node_w     = (const float*)d_in[3];
    const float* node_b     = (const float*)d_in[4];
    const float* edge_w     = (const float*)d_in[5];
    const float* edge_b     = (const float*)d_in[6];
    const float* lin_w      = (const float*)d_in[7];
    const float* lin_edge_w = (const float*)d_in[8];
    const float* att_src    = (const float*)d_in[9];
    const float* att_dst    = (const float*)d_in[10];
    const float* att_edge   = (const float*)d_in[11];
    const float* gat_bias   = (const float*)d_in[12];
    const float* ln_g       = (const float*)d_in[13];
    const float* ln_b       = (const float*)d_in[14];

    int NN = in_sizes[0] / 8;
    int E  = in_sizes[1] / 2;
    const int* src = ei;
    const int* dst = ei + E;

    int nbkt = (NN + 255) >> 8;                 // 391 for N=100000 (<= NBKT_MAX)
    int ntot = nbkt * P1B;                      // counter count
    int chunk = (E + P1B - 1) / P1B;

    char* wsp = (char*)d_ws;
    size_t off = 0;
    auto alloc = [&](size_t bytes) -> void* {
        off = (off + 255) & ~(size_t)255;
        void* p = wsp + off;
        off += bytes;
        return p;
    };
    ushort* h_bf    = (ushort*)alloc((size_t)NN * 64 * 2);
    ushort* xs2     = (ushort*)alloc((size_t)NN * 64 * 2);
    float*  a_src4  = (float*)alloc((size_t)NN * 4 * 4);
    float*  a_dst4  = (float*)alloc((size_t)NN * 4 * 4);
    uint2*  recs    = (uint2*)alloc((size_t)(E + 8) * 8);  // +8 sentinel pad
    uint2*  brec    = (uint2*)alloc((size_t)E * 8);
    float4* ea_mean = (float4*)alloc((size_t)NN * 16);
    int*    rowptr  = (int*)alloc((size_t)(NN + 1) * 4);
    int*    perm    = (int*)alloc((size_t)(nbkt * 256) * 4);
    int*    S       = (int*)alloc((size_t)ntot * 4);
    int*    bsum    = (int*)alloc(4096);
    float*  Mc      = (float*)alloc(256);

    int nodeb = (NN*64 + 255) / 256;
    k_prep0<<<1 + P1B + nodeb, 256, 0, stream>>>(
        lin_edge_w, att_edge, edge_w, edge_b, Mc, x, node_w, node_b, h_bf,
        dst, S, E, chunk, nbkt, NN);
    int nsb = (ntot + 1023) / 1024;
    k_scanA<<<nsb, 1024, 0, stream>>>(S, S, bsum, ntot);
    k_scanB<<<1, 1024, 0, stream>>>(bsum, nsb);
    k_scat1<<<P1B, 256, 0, stream>>>(dst, src, (const float4*)edge_attr,
                                     S, bsum, brec, E, chunk, nbkt);
    k_csrproj<<<nbkt + PROJB, 256, 0, stream>>>(brec, S, bsum, recs, rowptr, perm,
                                                ea_mean, nbkt, NN, E,
                                                h_bf, lin_w, att_src, att_dst,
                                                xs2, a_src4, a_dst4);

    for (int l = 0; l < 3; ++l) {
        if (l > 0)
            k_proj<<<PROJB, 256, 0, stream>>>(h_bf, lin_w + l*4096, att_src + l*64,
                                              att_dst + l*64, xs2, a_src4, a_dst4, NN);
        k_gat<<<(NN + 15) / 16, 256, 0, stream>>>((const uint4*)xs2, a_src4, a_dst4,
                                                  rowptr, recs, ea_mean, perm,
                                                  Mc + l*16, Mc + 48 + l*4,
                                                  gat_bias + l*64, ln_g + l*64, ln_b + l*64,
                                                  h_bf, h_bf, (float*)d_out,
                                                  (l == 2) ? 1 : 0, NN);
    }
}